// Round 5
// baseline (1393.569 us; speedup 1.0000x reference)
//
#include <hip/hip_runtime.h>
#include <cstdint>
#include <cstddef>

// B=1, N=768, CM=384, CP=128, H=12, SQK=SV=16, PQK=4, PV=8, NFIN=2112, NOUT=384
static constexpr float SCALAR_W = 0.14433756729740643f;  // 1/sqrt(3*16)
static constexpr float PTW_C    = 0.13608276348795434f;  // sqrt(1/(3*4*4.5))
static constexpr float RSQRT3   = 0.5773502691896258f;
static constexpr float FP16HUGE = 65504.0f;

// ws layout (floats)
static constexpr size_t OFF_P    = 0;          // 768*1152  [n][ q(192) | kv(384) | qp(144) | kvp(432) ]
static constexpr size_t OFF_R    = 884736;     // 768*9     [n][i*3+j]
static constexpr size_t OFF_QPG  = 891648;     // 768*144   [n][i*48 + h*4 + a]
static constexpr size_t OFF_KVPG = 1002240;    // 768*432   [n][i*144 + h*12 + e]
static constexpr size_t OFF_LG   = 1334016;    // 768*12*768  [n][h][m]  logits -> attn in place
static constexpr size_t OFF_PTG  = 8411904;    // 768*288   [n][i*96 + h*8 + c]  res_pt_g
static constexpr size_t OFF_FIN  = 8633088;    // 768*2112
static constexpr size_t WS_TOTAL = 10255104;   // floats = 41.02 MB

__global__ void k_sentinel(float* __restrict__ out, int nel, float val)
{
    const int i = blockIdx.x * 256 + threadIdx.x;
    if (i < nel) out[i] = val;
}

// P[r][colbase+col] = sum_k A[r][k]*B[k][col] + bias[col]; 1 thread/output
__global__ __launch_bounds__(256) void k_proj(const float* __restrict__ A,
    const float* __restrict__ Bm, const float* __restrict__ bias,
    float* __restrict__ P, int ncols, int colbase)
{
    const int o = blockIdx.x * 256 + threadIdx.x;
    if (o >= 768 * ncols) return;
    const int r = o / ncols, col = o - r * ncols;
    const float* a = A + (size_t)r * 384;
    float s = 0.f;
    for (int k = 0; k < 384; ++k) s += a[k] * Bm[(size_t)k * ncols + col];
    P[(size_t)r * 1152 + colbase + col] = s + bias[col];
}

// R[n][i][j] from normalized quat; 1 thread/element
__global__ __launch_bounds__(256) void k_rmat(const float* __restrict__ quat,
    float* __restrict__ ws)
{
    const int o = blockIdx.x * 256 + threadIdx.x;
    if (o >= 768 * 9) return;
    const int n = o / 9, e = o - 9 * n;
    const float q0 = quat[n*4+0], q1 = quat[n*4+1], q2 = quat[n*4+2], q3 = quat[n*4+3];
    const float inv = 1.0f / sqrtf(q0*q0 + q1*q1 + q2*q2 + q3*q3);
    const float w = q0*inv, x = q1*inv, y = q2*inv, z = q3*inv;
    float R[9];
    R[0] = 1.f - 2.f*(y*y + z*z); R[1] = 2.f*(x*y - w*z); R[2] = 2.f*(x*z + w*y);
    R[3] = 2.f*(x*y + w*z); R[4] = 1.f - 2.f*(x*x + z*z); R[5] = 2.f*(y*z - w*x);
    R[6] = 2.f*(x*z - w*y); R[7] = 2.f*(y*z + w*x); R[8] = 1.f - 2.f*(x*x + y*y);
    ws[OFF_R + o] = R[e];
}

// qp_g / kvp_g rigid transforms; 1 thread/element
__global__ __launch_bounds__(256) void k_rigid(const float* __restrict__ trans,
    float* __restrict__ ws)
{
    const int o = blockIdx.x * 256 + threadIdx.x;
    if (o >= 768 * 576) return;
    const int n = o / 576, e = o - 576 * n;
    const float* R = ws + OFF_R + (size_t)n * 9;
    if (e < 144) {                       // qp_g[n][i*48+p], p = h*4+a
        const int i = e / 48, p = e - 48 * i;
        const float* Pn = ws + OFF_P + (size_t)n * 1152 + 576;
        ws[OFF_QPG + (size_t)n*144 + e] =
            R[i*3+0]*Pn[p] + R[i*3+1]*Pn[48+p] + R[i*3+2]*Pn[96+p] + trans[n*3+i];
    } else {                             // kvp_g[n][i*144+p], p = h*12+e'
        const int e2 = e - 144;
        const int i = e2 / 144, p = e2 - 144 * i;
        const float* Pn = ws + OFF_P + (size_t)n * 1152 + 720;
        ws[OFF_KVPG + (size_t)n*432 + e2] =
            R[i*3+0]*Pn[p] + R[i*3+1]*Pn[144+p] + R[i*3+2]*Pn[288+p] + trans[n*3+i];
    }
}

// logits[n][h][m] = sc + pt - pen; 1 thread/element (o = n*9216 + h*768 + m)
__global__ __launch_bounds__(256) void k_logits(const float* __restrict__ maskp,
    const float* __restrict__ pw_raw, float* __restrict__ ws)
{
    const size_t o = (size_t)blockIdx.x * 256 + threadIdx.x;
    if (o >= (size_t)768 * 12 * 768) return;
    const int m = (int)(o % 768);
    const int nh = (int)(o / 768);
    const int h = nh % 12, n = nh / 12;
    const float* qs = ws + OFF_P + (size_t)n * 1152 + h * 16;         // q_s[n,h,:]
    const float* ks = ws + OFF_P + (size_t)m * 1152 + 192 + h * 32;   // k_s[m,h,:]
    float sc = 0.f;
    for (int k = 0; k < 16; ++k) sc += qs[k] * SCALAR_W * ks[k];
    const float* qp = ws + OFF_QPG + (size_t)n * 144;
    const float* kp = ws + OFF_KVPG + (size_t)m * 432;
    float d2 = 0.f;
    for (int i = 0; i < 3; ++i)
        for (int a = 0; a < 4; ++a) {
            const float dq = qp[i*48 + h*4 + a] - kp[i*144 + h*12 + a];
            d2 += dq * dq;
        }
    const float pw = PTW_C * logf(1.f + expf(pw_raw[h]));
    const float pen = FP16HUGE * (1.f - maskp[n] * maskp[m]);
    ws[OFF_LG + o] = sc - 0.5f * pw * d2 - pen;
}

// lg[n][h][m] += (in2d[n,m,:]@w2d[:,h] + b2d[h]) * rsqrt3; 1 thread per (n,m)
__global__ __launch_bounds__(256) void k_a2d(const float* __restrict__ in2d,
    const float* __restrict__ w2d, const float* __restrict__ b2d,
    float* __restrict__ ws)
{
    const int o = blockIdx.x * 256 + threadIdx.x;
    if (o >= 768 * 768) return;
    const int n = o / 768, m = o - 768 * n;
    const float* p = in2d + (size_t)o * 128;
    float acc[12] = {0,0,0,0,0,0,0,0,0,0,0,0};
    for (int c = 0; c < 128; ++c) {
        const float x = p[c];
        for (int h = 0; h < 12; ++h) acc[h] += x * w2d[c*12 + h];
    }
    float* lg = ws + OFF_LG + ((size_t)n * 12) * 768 + m;
    for (int h = 0; h < 12; ++h)
        lg[(size_t)h * 768] += (acc[h] + b2d[h]) * RSQRT3;
}

// softmax over m, serial, one thread per (n,h) row, in place
__global__ __launch_bounds__(256) void k_softmax(float* __restrict__ ws)
{
    const int o = blockIdx.x * 256 + threadIdx.x;
    if (o >= 768 * 12) return;
    float* lg = ws + OFF_LG + (size_t)o * 768;
    float mx = -3.0e38f;
    for (int m = 0; m < 768; ++m) mx = fmaxf(mx, lg[m]);
    float s = 0.f;
    for (int m = 0; m < 768; ++m) { const float e = expf(lg[m] - mx); lg[m] = e; s += e; }
    const float inv = 1.f / s;
    for (int m = 0; m < 768; ++m) lg[m] *= inv;
}

// res_s[n][h*16+d] -> fin[0..192); 1 thread/output
__global__ __launch_bounds__(256) void k_vs(float* __restrict__ ws)
{
    const int o = blockIdx.x * 256 + threadIdx.x;
    if (o >= 768 * 192) return;
    const int n = o / 192, q = o - 192 * n, h = q >> 4, d = q & 15;
    const float* at = ws + OFF_LG + ((size_t)n * 12 + h) * 768;
    const float* v  = ws + OFF_P + 192 + h*32 + 16 + d;       // v_s[m,h,d]
    float s = 0.f;
    for (int m = 0; m < 768; ++m) s += at[m] * v[(size_t)m * 1152];
    ws[OFF_FIN + (size_t)n * 2112 + q] = s;
}

// res_pt_g[n][i*96+h*8+c] -> OFF_PTG; 1 thread/output
__global__ __launch_bounds__(256) void k_vpt(float* __restrict__ ws)
{
    const int o = blockIdx.x * 256 + threadIdx.x;
    if (o >= 768 * 288) return;
    const int n = o / 288, q = o - 288 * n, i = q / 96, r = q - 96 * i;
    const int h = r >> 3, c = r & 7;
    const float* at = ws + OFF_LG + ((size_t)n * 12 + h) * 768;
    const float* v  = ws + OFF_KVPG + i*144 + h*12 + 4 + c;   // vp_g[m,i,h,c]
    float s = 0.f;
    for (int m = 0; m < 768; ++m) s += at[m] * v[(size_t)m * 432];
    ws[OFF_PTG + (size_t)o] = s;
}

// res_2d[n][h*128+c] -> fin[576..2112); 1 thread/output
__global__ __launch_bounds__(256) void k_v2d(const float* __restrict__ in2d,
    float* __restrict__ ws)
{
    const int o = blockIdx.x * 256 + threadIdx.x;
    if (o >= 768 * 1536) return;
    const int n = o / 1536, q = o - 1536 * n, h = q >> 7, c = q & 127;
    const float* at  = ws + OFF_LG + ((size_t)n * 12 + h) * 768;
    const float* col = in2d + (size_t)n * 768 * 128 + c;
    float s = 0.f;
    for (int m = 0; m < 768; ++m) s += at[m] * col[(size_t)m * 128];
    ws[OFF_FIN + (size_t)n * 2112 + 576 + q] = s;
}

// res_pt_l[n][i*96+p] = sum_j R[j][i]*(ptg[j*96+p]-trans[j]) -> fin[192..480)
__global__ __launch_bounds__(256) void k_epi(const float* __restrict__ trans,
    float* __restrict__ ws)
{
    const int o = blockIdx.x * 256 + threadIdx.x;
    if (o >= 768 * 288) return;
    const int n = o / 288, q = o - 288 * n, i = q / 96, p = q - 96 * i;
    const float* R = ws + OFF_R + (size_t)n * 9;
    const float* g = ws + OFF_PTG + (size_t)n * 288;
    float s = 0.f;
    for (int j = 0; j < 3; ++j) s += R[j*3 + i] * (g[j*96 + p] - trans[n*3 + j]);
    ws[OFF_FIN + (size_t)n * 2112 + 192 + q] = s;
}

// pt_norm[n][p] -> fin[480..576)
__global__ __launch_bounds__(256) void k_norm(float* __restrict__ ws)
{
    const int o = blockIdx.x * 256 + threadIdx.x;
    if (o >= 768 * 96) return;
    const int n = o / 96, p = o - 96 * n;
    const float* f = ws + OFF_FIN + (size_t)n * 2112 + 192;
    const float a = f[p], b = f[96 + p], c = f[192 + p];
    ws[OFF_FIN + (size_t)n * 2112 + 480 + p] = sqrtf(1e-8f + a*a + b*b + c*c);
}

// out[n][c] = fin[n] @ wout[:,c] + bout[c]
__global__ __launch_bounds__(256) void k_final(const float* __restrict__ wout,
    const float* __restrict__ bout, const float* __restrict__ ws,
    float* __restrict__ out)
{
    const int o = blockIdx.x * 256 + threadIdx.x;
    if (o >= 768 * 384) return;
    const int n = o / 384, c = o - 384 * n;
    const float* f = ws + OFF_FIN + (size_t)n * 2112;
    float s = 0.f;
    for (int k = 0; k < 2112; ++k) s += f[k] * wout[(size_t)k * 384 + c];
    out[o] = s + bout[c];
}

// ---------------------------------------------------------------------------
extern "C" void kernel_launch(void* const* d_in, const int* in_sizes, int n_in,
                              void* d_out, int out_size, void* d_ws, size_t ws_size,
                              hipStream_t stream)
{
    const float* in1d  = (const float*)d_in[0];
    const float* in2d  = (const float*)d_in[1];
    const float* maskp = (const float*)d_in[2];
    const float* quat  = (const float*)d_in[3];
    const float* trans = (const float*)d_in[4];
    const float* wq    = (const float*)d_in[5];
    const float* bq    = (const float*)d_in[6];
    const float* wkv   = (const float*)d_in[7];
    const float* bkv   = (const float*)d_in[8];
    const float* wqp   = (const float*)d_in[9];
    const float* bqp   = (const float*)d_in[10];
    const float* wkvp  = (const float*)d_in[11];
    const float* bkvp  = (const float*)d_in[12];
    const float* pwr   = (const float*)d_in[13];
    const float* w2d   = (const float*)d_in[14];
    const float* b2d   = (const float*)d_in[15];
    const float* wout  = (const float*)d_in[16];
    const float* bout  = (const float*)d_in[17];
    float* ws  = (float*)d_ws;
    float* out = (float*)d_out;

    if (ws_size < WS_TOTAL * sizeof(float)) {
        const float val = 1000.0f + (float)(ws_size / (1024.0 * 1024.0));
        k_sentinel<<<dim3((out_size + 255) / 256), dim3(256), 0, stream>>>(out, out_size, val);
        return;
    }

    dim3 blk(256);
    k_proj<<<dim3((768*192 + 255)/256), blk, 0, stream>>>(in1d, wq,   bq,   ws, 192, 0);
    k_proj<<<dim3((768*384 + 255)/256), blk, 0, stream>>>(in1d, wkv,  bkv,  ws, 384, 192);
    k_proj<<<dim3((768*144 + 255)/256), blk, 0, stream>>>(in1d, wqp,  bqp,  ws, 144, 576);
    k_proj<<<dim3((768*432 + 255)/256), blk, 0, stream>>>(in1d, wkvp, bkvp, ws, 432, 720);
    k_rmat<<<dim3((768*9 + 255)/256), blk, 0, stream>>>(quat, ws);
    k_rigid<<<dim3((768*576 + 255)/256), blk, 0, stream>>>(trans, ws);
    k_logits<<<dim3((768*12*768 + 255)/256), blk, 0, stream>>>(maskp, pwr, ws);
    k_a2d<<<dim3((768*768 + 255)/256), blk, 0, stream>>>(in2d, w2d, b2d, ws);
    k_softmax<<<dim3((768*12 + 255)/256), blk, 0, stream>>>(ws);
    k_vs<<<dim3((768*192 + 255)/256), blk, 0, stream>>>(ws);
    k_vpt<<<dim3((768*288 + 255)/256), blk, 0, stream>>>(ws);
    k_v2d<<<dim3((768*1536 + 255)/256), blk, 0, stream>>>(in2d, ws);
    k_epi<<<dim3((768*288 + 255)/256), blk, 0, stream>>>(trans, ws);
    k_norm<<<dim3((768*96 + 255)/256), blk, 0, stream>>>(ws);
    k_final<<<dim3((768*384 + 255)/256), blk, 0, stream>>>(wout, bout, ws, out);
}

// Round 6
// 1300.648 us; speedup vs baseline: 1.0714x; 1.0714x over previous
//
#include <hip/hip_runtime.h>
#include <cstdint>
#include <cstddef>

// B=1, N=768, CM=384, CP=128, H=12, SQK=SV=16, PQK=4, PV=8, NFIN=2112, NOUT=384
static constexpr float SCALAR_W = 0.14433756729740643f;  // 1/sqrt(3*16)
static constexpr float PTW_C    = 0.13608276348795434f;  // sqrt(1/(3*4*4.5))
static constexpr float RSQRT3   = 0.5773502691896258f;
static constexpr float FP16HUGE = 65504.0f;

// ws layout (floats) — identical to round-5 anchor
static constexpr size_t OFF_P    = 0;          // 768*1152  [n][ q(192) | kv(384) | qp(144) | kvp(432) ]
static constexpr size_t OFF_R    = 884736;     // 768*9     [n][i*3+j]
static constexpr size_t OFF_QPG  = 891648;     // 768*144   [n][i*48 + h*4 + a]
static constexpr size_t OFF_KVPG = 1002240;    // 768*432   [n][i*144 + h*12 + e]
static constexpr size_t OFF_LG   = 1334016;    // 768*12*768  [n][h][m]  logits -> attn in place
static constexpr size_t OFF_PTG  = 8411904;    // 768*288   [n][i*96 + h*8 + c]  res_pt_g
static constexpr size_t OFF_FIN  = 8633088;    // 768*2112
static constexpr size_t WS_TOTAL = 10255104;   // floats = 41.02 MB

__global__ void k_sentinel(float* __restrict__ out, int nel, float val)
{
    const int i = blockIdx.x * 256 + threadIdx.x;
    if (i < nel) out[i] = val;
}

// ---------------------------------------------------------------------------
// Tiled projection: P[r][colbase+col] = sum_k A[r][k]*B[k][col] + bias[col]
// 8 rows of A staged in LDS per block; 256 threads over cols.
// ---------------------------------------------------------------------------
__global__ __launch_bounds__(256) void k_proj(const float* __restrict__ A,
    const float* __restrict__ Bm, const float* __restrict__ bias,
    float* __restrict__ P, int ncols, int colbase)
{
    __shared__ float At[8][384];
    const int t = threadIdx.x;
    const int r0 = blockIdx.y * 8;
    const float4* A4 = reinterpret_cast<const float4*>(A + (size_t)r0 * 384);
    float4* At4 = reinterpret_cast<float4*>(&At[0][0]);
#pragma unroll
    for (int i = 0; i < 3; ++i) At4[t + 256 * i] = A4[t + 256 * i];  // 768 float4
    __syncthreads();
    const int col = blockIdx.x * 256 + t;
    if (col >= ncols) return;
    float acc[8] = {0.f,0.f,0.f,0.f,0.f,0.f,0.f,0.f};
    const float* bp = Bm + col;
#pragma unroll 4
    for (int k = 0; k < 384; ++k) {
        const float b = bp[(size_t)k * ncols];
#pragma unroll
        for (int r = 0; r < 8; ++r) acc[r] += At[r][k] * b;
    }
    const float bb = bias[col];
#pragma unroll
    for (int r = 0; r < 8; ++r)
        P[(size_t)(r0 + r) * 1152 + colbase + col] = acc[r] + bb;
}

// R[n][i][j] from normalized quat; 1 thread/element  (unchanged)
__global__ __launch_bounds__(256) void k_rmat(const float* __restrict__ quat,
    float* __restrict__ ws)
{
    const int o = blockIdx.x * 256 + threadIdx.x;
    if (o >= 768 * 9) return;
    const int n = o / 9, e = o - 9 * n;
    const float q0 = quat[n*4+0], q1 = quat[n*4+1], q2 = quat[n*4+2], q3 = quat[n*4+3];
    const float inv = 1.0f / sqrtf(q0*q0 + q1*q1 + q2*q2 + q3*q3);
    const float w = q0*inv, x = q1*inv, y = q2*inv, z = q3*inv;
    float R[9];
    R[0] = 1.f - 2.f*(y*y + z*z); R[1] = 2.f*(x*y - w*z); R[2] = 2.f*(x*z + w*y);
    R[3] = 2.f*(x*y + w*z); R[4] = 1.f - 2.f*(x*x + z*z); R[5] = 2.f*(y*z - w*x);
    R[6] = 2.f*(x*z - w*y); R[7] = 2.f*(y*z + w*x); R[8] = 1.f - 2.f*(x*x + y*y);
    ws[OFF_R + o] = R[e];
}

// qp_g / kvp_g rigid transforms; 1 thread/element  (unchanged)
__global__ __launch_bounds__(256) void k_rigid(const float* __restrict__ trans,
    float* __restrict__ ws)
{
    const int o = blockIdx.x * 256 + threadIdx.x;
    if (o >= 768 * 576) return;
    const int n = o / 576, e = o - 576 * n;
    const float* R = ws + OFF_R + (size_t)n * 9;
    if (e < 144) {
        const int i = e / 48, p = e - 48 * i;
        const float* Pn = ws + OFF_P + (size_t)n * 1152 + 576;
        ws[OFF_QPG + (size_t)n*144 + e] =
            R[i*3+0]*Pn[p] + R[i*3+1]*Pn[48+p] + R[i*3+2]*Pn[96+p] + trans[n*3+i];
    } else {
        const int e2 = e - 144;
        const int i = e2 / 144, p = e2 - 144 * i;
        const float* Pn = ws + OFF_P + (size_t)n * 1152 + 720;
        ws[OFF_KVPG + (size_t)n*432 + e2] =
            R[i*3+0]*Pn[p] + R[i*3+1]*Pn[144+p] + R[i*3+2]*Pn[288+p] + trans[n*3+i];
    }
}

// logits[n][h][m] = sc + pt - pen; 1 thread/element  (unchanged)
__global__ __launch_bounds__(256) void k_logits(const float* __restrict__ maskp,
    const float* __restrict__ pw_raw, float* __restrict__ ws)
{
    const size_t o = (size_t)blockIdx.x * 256 + threadIdx.x;
    if (o >= (size_t)768 * 12 * 768) return;
    const int m = (int)(o % 768);
    const int nh = (int)(o / 768);
    const int h = nh % 12, n = nh / 12;
    const float* qs = ws + OFF_P + (size_t)n * 1152 + h * 16;
    const float* ks = ws + OFF_P + (size_t)m * 1152 + 192 + h * 32;
    float sc = 0.f;
    for (int k = 0; k < 16; ++k) sc += qs[k] * SCALAR_W * ks[k];
    const float* qp = ws + OFF_QPG + (size_t)n * 144;
    const float* kp = ws + OFF_KVPG + (size_t)m * 432;
    float d2 = 0.f;
    for (int i = 0; i < 3; ++i)
        for (int a = 0; a < 4; ++a) {
            const float dq = qp[i*48 + h*4 + a] - kp[i*144 + h*12 + a];
            d2 += dq * dq;
        }
    const float pw = PTW_C * logf(1.f + expf(pw_raw[h]));
    const float pen = FP16HUGE * (1.f - maskp[n] * maskp[m]);
    ws[OFF_LG + o] = sc - 0.5f * pw * d2 - pen;
}

// ---------------------------------------------------------------------------
// a2d: lg[n][h][m] += (in2d[n,m,:]@w2d[:,h] + b2d[h]) * rsqrt3
// Block = (n, 128-m tile). Thread quad (cg=0..3) owns a row; float4 loads;
// 4-lane shuffle reduce. Wave working set 8 KB (vs 32 KB before).
// ---------------------------------------------------------------------------
__global__ __launch_bounds__(256) void k_a2d(const float* __restrict__ in2d,
    const float* __restrict__ w2d, const float* __restrict__ b2d,
    float* __restrict__ ws)
{
    __shared__ float w2l[1536];
    const int n = blockIdx.x, mt = blockIdx.y, t = threadIdx.x;
    for (int i = t; i < 1536; i += 256) w2l[i] = w2d[i];
    __syncthreads();
    const int cg = t & 3, pr = t >> 2;   // 64 row-quads
#pragma unroll
    for (int half = 0; half < 2; ++half) {
        const int m = mt * 128 + half * 64 + pr;
        const float* p = in2d + ((size_t)n * 768 + m) * 128 + cg * 32;
        float acc[12] = {0,0,0,0,0,0,0,0,0,0,0,0};
#pragma unroll
        for (int cq = 0; cq < 8; ++cq) {
            const float4 v = *reinterpret_cast<const float4*>(p + cq * 4);
#pragma unroll
            for (int j = 0; j < 4; ++j) {
                const float x = (&v.x)[j];
                const int c = cg * 32 + cq * 4 + j;
#pragma unroll
                for (int h = 0; h < 12; ++h) acc[h] += x * w2l[c * 12 + h];
            }
        }
#pragma unroll
        for (int h = 0; h < 12; ++h) {
            acc[h] += __shfl_xor(acc[h], 1);
            acc[h] += __shfl_xor(acc[h], 2);
        }
        if (cg == 0) {
            float* lgp = ws + OFF_LG + ((size_t)n * 12) * 768 + m;
#pragma unroll
            for (int h = 0; h < 12; ++h)
                lgp[(size_t)h * 768] += (acc[h] + b2d[h]) * RSQRT3;
        }
    }
}

// ---------------------------------------------------------------------------
// softmax: one wave per (n,h) row, in place.
// ---------------------------------------------------------------------------
__global__ __launch_bounds__(256) void k_softmax(float* __restrict__ ws)
{
    const int wid = (blockIdx.x * 256 + threadIdx.x) >> 6;
    const int lane = threadIdx.x & 63;
    if (wid >= 768 * 12) return;
    float* lg = ws + OFF_LG + (size_t)wid * 768;
    float v[12];
    float mx = -3.0e38f;
#pragma unroll
    for (int i = 0; i < 12; ++i) { v[i] = lg[lane + i*64]; mx = fmaxf(mx, v[i]); }
#pragma unroll
    for (int off = 32; off > 0; off >>= 1) mx = fmaxf(mx, __shfl_xor(mx, off));
    float s = 0.f;
#pragma unroll
    for (int i = 0; i < 12; ++i) { v[i] = expf(v[i] - mx); s += v[i]; }
#pragma unroll
    for (int off = 32; off > 0; off >>= 1) s += __shfl_xor(s, off);
    const float inv = 1.f / s;
#pragma unroll
    for (int i = 0; i < 12; ++i) lg[lane + i*64] = v[i] * inv;
}

// res_s[n][h*16+d] -> fin[0..192); 1 thread/output  (unchanged)
__global__ __launch_bounds__(256) void k_vs(float* __restrict__ ws)
{
    const int o = blockIdx.x * 256 + threadIdx.x;
    if (o >= 768 * 192) return;
    const int n = o / 192, q = o - 192 * n, h = q >> 4, d = q & 15;
    const float* at = ws + OFF_LG + ((size_t)n * 12 + h) * 768;
    const float* v  = ws + OFF_P + 192 + h*32 + 16 + d;
    float s = 0.f;
    for (int m = 0; m < 768; ++m) s += at[m] * v[(size_t)m * 1152];
    ws[OFF_FIN + (size_t)n * 2112 + q] = s;
}

// res_pt_g[n][i*96+h*8+c] -> OFF_PTG; 1 thread/output  (unchanged)
__global__ __launch_bounds__(256) void k_vpt(float* __restrict__ ws)
{
    const int o = blockIdx.x * 256 + threadIdx.x;
    if (o >= 768 * 288) return;
    const int n = o / 288, q = o - 288 * n, i = q / 96, r = q - 96 * i;
    const int h = r >> 3, c = r & 7;
    const float* at = ws + OFF_LG + ((size_t)n * 12 + h) * 768;
    const float* v  = ws + OFF_KVPG + i*144 + h*12 + 4 + c;
    float s = 0.f;
    for (int m = 0; m < 768; ++m) s += at[m] * v[(size_t)m * 432];
    ws[OFF_PTG + (size_t)o] = s;
}

// ---------------------------------------------------------------------------
// res_2d: one block per n. attn[12][768] staged in LDS; single coalesced
// pass over in2d[n,:,:]; thread owns (c, 6 h's).
// ---------------------------------------------------------------------------
__global__ __launch_bounds__(256) void k_v2d(const float* __restrict__ in2d,
    float* __restrict__ ws)
{
    __shared__ float at[12 * 768];
    const int n = blockIdx.x, t = threadIdx.x;
    {
        const float4* a4 = reinterpret_cast<const float4*>(ws + OFF_LG + (size_t)n * 9216);
        float4* l4 = reinterpret_cast<float4*>(at);
        for (int i = t; i < 2304; i += 256) l4[i] = a4[i];
    }
    __syncthreads();
    const int c = t & 127, hg = t >> 7;   // hg=0 -> h 0..5, hg=1 -> h 6..11
    const float* p = in2d + (size_t)n * 768 * 128 + c;
    float acc[6] = {0,0,0,0,0,0};
    for (int m = 0; m < 768; ++m) {
        const float x = p[(size_t)m * 128];
#pragma unroll
        for (int j = 0; j < 6; ++j) acc[j] += at[(hg*6 + j) * 768 + m] * x;
    }
    float* fo = ws + OFF_FIN + (size_t)n * 2112 + 576;
#pragma unroll
    for (int j = 0; j < 6; ++j) fo[(hg*6 + j) * 128 + c] = acc[j];
}

// res_pt_l -> fin[192..480)  (unchanged)
__global__ __launch_bounds__(256) void k_epi(const float* __restrict__ trans,
    float* __restrict__ ws)
{
    const int o = blockIdx.x * 256 + threadIdx.x;
    if (o >= 768 * 288) return;
    const int n = o / 288, q = o - 288 * n, i = q / 96, p = q - 96 * i;
    const float* R = ws + OFF_R + (size_t)n * 9;
    const float* g = ws + OFF_PTG + (size_t)n * 288;
    float s = 0.f;
    for (int j = 0; j < 3; ++j) s += R[j*3 + i] * (g[j*96 + p] - trans[n*3 + j]);
    ws[OFF_FIN + (size_t)n * 2112 + 192 + q] = s;
}

// pt_norm -> fin[480..576)  (unchanged)
__global__ __launch_bounds__(256) void k_norm(float* __restrict__ ws)
{
    const int o = blockIdx.x * 256 + threadIdx.x;
    if (o >= 768 * 96) return;
    const int n = o / 96, p = o - 96 * n;
    const float* f = ws + OFF_FIN + (size_t)n * 2112 + 192;
    const float a = f[p], b = f[96 + p], c = f[192 + p];
    ws[OFF_FIN + (size_t)n * 2112 + 480 + p] = sqrtf(1e-8f + a*a + b*b + c*c);
}

// ---------------------------------------------------------------------------
// Final GEMM (tiled): out[768][384] = fin[768][2112] @ wout + bout
// 8 fin rows staged per block; grid (3, 96).
// ---------------------------------------------------------------------------
__global__ __launch_bounds__(256) void k_final(const float* __restrict__ wout,
    const float* __restrict__ bout, const float* __restrict__ ws,
    float* __restrict__ out)
{
    __shared__ float At[8][256];
    const float* fin = ws + OFF_FIN;
    const int r0 = blockIdx.y * 8;
    const int c0 = blockIdx.x * 128;
    const int t = threadIdx.x;
    const int c = t & 127, half = t >> 7;
    float acc[4] = {0.f, 0.f, 0.f, 0.f};
    for (int k0 = 0; k0 < 2112; k0 += 256) {
        const int kc = (2112 - k0 < 256) ? (2112 - k0) : 256;
        __syncthreads();
        const int kq = kc / 4;
        const int nf4 = 8 * kq;
        for (int i = t; i < nf4; i += 256) {
            const int r = i / kq, j = i - r * kq;
            *reinterpret_cast<float4*>(&At[r][j * 4]) =
                *reinterpret_cast<const float4*>(&fin[(size_t)(r0 + r) * 2112 + k0 + j * 4]);
        }
        __syncthreads();
#pragma unroll 4
        for (int k = 0; k < kc; ++k) {
            const float b = wout[(size_t)(k0 + k) * 384 + c0 + c];
#pragma unroll
            for (int r = 0; r < 4; ++r) acc[r] += At[half*4 + r][k] * b;
        }
    }
#pragma unroll
    for (int r = 0; r < 4; ++r)
        out[(size_t)(r0 + half*4 + r) * 384 + c0 + c] = acc[r] + bout[c0 + c];
}

// ---------------------------------------------------------------------------
extern "C" void kernel_launch(void* const* d_in, const int* in_sizes, int n_in,
                              void* d_out, int out_size, void* d_ws, size_t ws_size,
                              hipStream_t stream)
{
    const float* in1d  = (const float*)d_in[0];
    const float* in2d  = (const float*)d_in[1];
    const float* maskp = (const float*)d_in[2];
    const float* quat  = (const float*)d_in[3];
    const float* trans = (const float*)d_in[4];
    const float* wq    = (const float*)d_in[5];
    const float* bq    = (const float*)d_in[6];
    const float* wkv   = (const float*)d_in[7];
    const float* bkv   = (const float*)d_in[8];
    const float* wqp   = (const float*)d_in[9];
    const float* bqp   = (const float*)d_in[10];
    const float* wkvp  = (const float*)d_in[11];
    const float* bkvp  = (const float*)d_in[12];
    const float* pwr   = (const float*)d_in[13];
    const float* w2d   = (const float*)d_in[14];
    const float* b2d   = (const float*)d_in[15];
    const float* wout  = (const float*)d_in[16];
    const float* bout  = (const float*)d_in[17];
    float* ws  = (float*)d_ws;
    float* out = (float*)d_out;

    if (ws_size < WS_TOTAL * sizeof(float)) {
        const float val = 1000.0f + (float)(ws_size / (1024.0 * 1024.0));
        k_sentinel<<<dim3((out_size + 255) / 256), dim3(256), 0, stream>>>(out, out_size, val);
        return;
    }

    dim3 blk(256);
    k_proj<<<dim3(1, 96), blk, 0, stream>>>(in1d, wq,   bq,   ws, 192, 0);
    k_proj<<<dim3(2, 96), blk, 0, stream>>>(in1d, wkv,  bkv,  ws, 384, 192);
    k_proj<<<dim3(1, 96), blk, 0, stream>>>(in1d, wqp,  bqp,  ws, 144, 576);
    k_proj<<<dim3(2, 96), blk, 0, stream>>>(in1d, wkvp, bkvp, ws, 432, 720);
    k_rmat<<<dim3((768*9 + 255)/256), blk, 0, stream>>>(quat, ws);
    k_rigid<<<dim3((768*576 + 255)/256), blk, 0, stream>>>(trans, ws);
    k_logits<<<dim3((768*12*768 + 255)/256), blk, 0, stream>>>(maskp, pwr, ws);
    k_a2d<<<dim3(768, 6), blk, 0, stream>>>(in2d, w2d, b2d, ws);
    k_softmax<<<dim3(2304), blk, 0, stream>>>(ws);
    k_vs<<<dim3((768*192 + 255)/256), blk, 0, stream>>>(ws);
    k_vpt<<<dim3((768*288 + 255)/256), blk, 0, stream>>>(ws);
    k_v2d<<<dim3(768), blk, 0, stream>>>(in2d, ws);
    k_epi<<<dim3((768*288 + 255)/256), blk, 0, stream>>>(trans, ws);
    k_norm<<<dim3((768*96 + 255)/256), blk, 0, stream>>>(ws);
    k_final<<<dim3(3, 96), blk, 0, stream>>>(wout, bout, ws, out);
}

// Round 7
// 1116.787 us; speedup vs baseline: 1.2478x; 1.1646x over previous
//
#include <hip/hip_runtime.h>
#include <cstdint>
#include <cstddef>

// B=1, N=768, CM=384, CP=128, H=12, SQK=SV=16, PQK=4, PV=8, NFIN=2112, NOUT=384
static constexpr float SCALAR_W = 0.14433756729740643f;  // 1/sqrt(3*16)
static constexpr float PTW_C    = 0.13608276348795434f;  // sqrt(1/(3*4*4.5))
static constexpr float RSQRT3   = 0.5773502691896258f;
static constexpr float FP16HUGE = 65504.0f;

// ws layout (floats)
static constexpr size_t OFF_P    = 0;          // 768*1152  [n][ q(192) | kv(384) | qp(144) | kvp(432) ]
static constexpr size_t OFF_R    = 884736;     // 768*9     [n][i*3+j]
static constexpr size_t OFF_QPG  = 891648;     // 768*144   [n][i*48 + h*4 + a]
static constexpr size_t OFF_KVPG = 1002240;    // 768*432   [n][i*144 + h*12 + e]
static constexpr size_t OFF_LG   = 1334016;    // 768*12*768  [n][h][m]  logits -> attn in place
static constexpr size_t OFF_PTG  = 8411904;    // 768*288   [n][i*96 + h*8 + c]  res_pt_g
static constexpr size_t OFF_FIN  = 8633088;    // 768*2112
static constexpr size_t OFF_VCAT = 10255104;   // 768*480   [m][ v_s(192) | vp_g(288) ]
static constexpr size_t WS_TOTAL = 10623744;   // floats = 42.5 MB

__global__ void k_sentinel(float* __restrict__ out, int nel, float val)
{
    const int i = blockIdx.x * 256 + threadIdx.x;
    if (i < nel) out[i] = val;
}

// ---------------------------------------------------------------------------
// Tiled projection (unchanged from R6)
// ---------------------------------------------------------------------------
__global__ __launch_bounds__(256) void k_proj(const float* __restrict__ A,
    const float* __restrict__ Bm, const float* __restrict__ bias,
    float* __restrict__ P, int ncols, int colbase)
{
    __shared__ float At[8][384];
    const int t = threadIdx.x;
    const int r0 = blockIdx.y * 8;
    const float4* A4 = reinterpret_cast<const float4*>(A + (size_t)r0 * 384);
    float4* At4 = reinterpret_cast<float4*>(&At[0][0]);
#pragma unroll
    for (int i = 0; i < 3; ++i) At4[t + 256 * i] = A4[t + 256 * i];
    __syncthreads();
    const int col = blockIdx.x * 256 + t;
    if (col >= ncols) return;
    float acc[8] = {0.f,0.f,0.f,0.f,0.f,0.f,0.f,0.f};
    const float* bp = Bm + col;
#pragma unroll 4
    for (int k = 0; k < 384; ++k) {
        const float b = bp[(size_t)k * ncols];
#pragma unroll
        for (int r = 0; r < 8; ++r) acc[r] += At[r][k] * b;
    }
    const float bb = bias[col];
#pragma unroll
    for (int r = 0; r < 8; ++r)
        P[(size_t)(r0 + r) * 1152 + colbase + col] = acc[r] + bb;
}

// R[n][i][j]  (unchanged)
__global__ __launch_bounds__(256) void k_rmat(const float* __restrict__ quat,
    float* __restrict__ ws)
{
    const int o = blockIdx.x * 256 + threadIdx.x;
    if (o >= 768 * 9) return;
    const int n = o / 9, e = o - 9 * n;
    const float q0 = quat[n*4+0], q1 = quat[n*4+1], q2 = quat[n*4+2], q3 = quat[n*4+3];
    const float inv = 1.0f / sqrtf(q0*q0 + q1*q1 + q2*q2 + q3*q3);
    const float w = q0*inv, x = q1*inv, y = q2*inv, z = q3*inv;
    float R[9];
    R[0] = 1.f - 2.f*(y*y + z*z); R[1] = 2.f*(x*y - w*z); R[2] = 2.f*(x*z + w*y);
    R[3] = 2.f*(x*y + w*z); R[4] = 1.f - 2.f*(x*x + z*z); R[5] = 2.f*(y*z - w*x);
    R[6] = 2.f*(x*z - w*y); R[7] = 2.f*(y*z + w*x); R[8] = 1.f - 2.f*(x*x + y*y);
    ws[OFF_R + o] = R[e];
}

// qp_g / kvp_g  (unchanged)
__global__ __launch_bounds__(256) void k_rigid(const float* __restrict__ trans,
    float* __restrict__ ws)
{
    const int o = blockIdx.x * 256 + threadIdx.x;
    if (o >= 768 * 576) return;
    const int n = o / 576, e = o - 576 * n;
    const float* R = ws + OFF_R + (size_t)n * 9;
    if (e < 144) {
        const int i = e / 48, p = e - 48 * i;
        const float* Pn = ws + OFF_P + (size_t)n * 1152 + 576;
        ws[OFF_QPG + (size_t)n*144 + e] =
            R[i*3+0]*Pn[p] + R[i*3+1]*Pn[48+p] + R[i*3+2]*Pn[96+p] + trans[n*3+i];
    } else {
        const int e2 = e - 144;
        const int i = e2 / 144, p = e2 - 144 * i;
        const float* Pn = ws + OFF_P + (size_t)n * 1152 + 720;
        ws[OFF_KVPG + (size_t)n*432 + e2] =
            R[i*3+0]*Pn[p] + R[i*3+1]*Pn[144+p] + R[i*3+2]*Pn[288+p] + trans[n*3+i];
    }
}

// VCAT[m][480] = [ v_s(192) | vp_g(288, i*96+h*8+c) ]
__global__ __launch_bounds__(256) void k_vcat(float* __restrict__ ws)
{
    const int o = blockIdx.x * 256 + threadIdx.x;
    if (o >= 768 * 480) return;
    const int m = o / 480, q = o - 480 * m;
    float v;
    if (q < 192) {
        const int h = q >> 4, d = q & 15;
        v = ws[OFF_P + (size_t)m*1152 + 192 + h*32 + 16 + d];
    } else {
        const int q2 = q - 192;
        const int i = q2 / 96, r = q2 - 96*i, h = r >> 3, c = r & 7;
        v = ws[OFF_KVPG + (size_t)m*432 + i*144 + h*12 + 4 + c];
    }
    ws[OFF_VCAT + o] = v;
}

// logits  (unchanged)
__global__ __launch_bounds__(256) void k_logits(const float* __restrict__ maskp,
    const float* __restrict__ pw_raw, float* __restrict__ ws)
{
    const size_t o = (size_t)blockIdx.x * 256 + threadIdx.x;
    if (o >= (size_t)768 * 12 * 768) return;
    const int m = (int)(o % 768);
    const int nh = (int)(o / 768);
    const int h = nh % 12, n = nh / 12;
    const float* qs = ws + OFF_P + (size_t)n * 1152 + h * 16;
    const float* ks = ws + OFF_P + (size_t)m * 1152 + 192 + h * 32;
    float sc = 0.f;
    for (int k = 0; k < 16; ++k) sc += qs[k] * SCALAR_W * ks[k];
    const float* qp = ws + OFF_QPG + (size_t)n * 144;
    const float* kp = ws + OFF_KVPG + (size_t)m * 432;
    float d2 = 0.f;
    for (int i = 0; i < 3; ++i)
        for (int a = 0; a < 4; ++a) {
            const float dq = qp[i*48 + h*4 + a] - kp[i*144 + h*12 + a];
            d2 += dq * dq;
        }
    const float pw = PTW_C * logf(1.f + expf(pw_raw[h]));
    const float pen = FP16HUGE * (1.f - maskp[n] * maskp[m]);
    ws[OFF_LG + o] = sc - 0.5f * pw * d2 - pen;
}

// a2d  (unchanged from R6)
__global__ __launch_bounds__(256) void k_a2d(const float* __restrict__ in2d,
    const float* __restrict__ w2d, const float* __restrict__ b2d,
    float* __restrict__ ws)
{
    __shared__ float w2l[1536];
    const int n = blockIdx.x, mt = blockIdx.y, t = threadIdx.x;
    for (int i = t; i < 1536; i += 256) w2l[i] = w2d[i];
    __syncthreads();
    const int cg = t & 3, pr = t >> 2;
#pragma unroll
    for (int half = 0; half < 2; ++half) {
        const int m = mt * 128 + half * 64 + pr;
        const float* p = in2d + ((size_t)n * 768 + m) * 128 + cg * 32;
        float acc[12] = {0,0,0,0,0,0,0,0,0,0,0,0};
#pragma unroll
        for (int cq = 0; cq < 8; ++cq) {
            const float4 v = *reinterpret_cast<const float4*>(p + cq * 4);
#pragma unroll
            for (int j = 0; j < 4; ++j) {
                const float x = (&v.x)[j];
                const int c = cg * 32 + cq * 4 + j;
#pragma unroll
                for (int h = 0; h < 12; ++h) acc[h] += x * w2l[c * 12 + h];
            }
        }
#pragma unroll
        for (int h = 0; h < 12; ++h) {
            acc[h] += __shfl_xor(acc[h], 1);
            acc[h] += __shfl_xor(acc[h], 2);
        }
        if (cg == 0) {
            float* lgp = ws + OFF_LG + ((size_t)n * 12) * 768 + m;
#pragma unroll
            for (int h = 0; h < 12; ++h)
                lgp[(size_t)h * 768] += (acc[h] + b2d[h]) * RSQRT3;
        }
    }
}

// softmax  (unchanged from R6)
__global__ __launch_bounds__(256) void k_softmax(float* __restrict__ ws)
{
    const int wid = (blockIdx.x * 256 + threadIdx.x) >> 6;
    const int lane = threadIdx.x & 63;
    if (wid >= 768 * 12) return;
    float* lg = ws + OFF_LG + (size_t)wid * 768;
    float v[12];
    float mx = -3.0e38f;
#pragma unroll
    for (int i = 0; i < 12; ++i) { v[i] = lg[lane + i*64]; mx = fmaxf(mx, v[i]); }
#pragma unroll
    for (int off = 32; off > 0; off >>= 1) mx = fmaxf(mx, __shfl_xor(mx, off));
    float s = 0.f;
#pragma unroll
    for (int i = 0; i < 12; ++i) { v[i] = expf(v[i] - mx); s += v[i]; }
#pragma unroll
    for (int off = 32; off > 0; off >>= 1) s += __shfl_xor(s, off);
    const float inv = 1.f / s;
#pragma unroll
    for (int i = 0; i < 12; ++i) lg[lane + i*64] = v[i] * inv;
}

// ---------------------------------------------------------------------------
// res_s + res_pt_g via VCAT: one block per n; attn row in LDS (padded);
// coalesced streaming of VCAT columns.
// ---------------------------------------------------------------------------
__global__ __launch_bounds__(512) void k_vsp(float* __restrict__ ws)
{
    __shared__ float at[12][776];
    const int n = blockIdx.x, t = threadIdx.x;
    {
        const float4* a4 = reinterpret_cast<const float4*>(ws + OFF_LG + (size_t)n * 9216);
        for (int i = t; i < 2304; i += 512) {
            const int row = i / 192, j = i - row * 192;
            *reinterpret_cast<float4*>(&at[row][j * 4]) = a4[i];
        }
    }
    __syncthreads();
    if (t >= 480) return;
    int h;
    if (t < 192) h = t >> 4;
    else { const int r = (t - 192) % 96; h = r >> 3; }
    const float* v = ws + OFF_VCAT + t;
    const float* a = &at[h][0];
    float s = 0.f;
    for (int m = 0; m < 768; ++m) s += a[m] * v[(size_t)m * 480];
    if (t < 192) ws[OFF_FIN + (size_t)n * 2112 + t] = s;
    else         ws[OFF_PTG + (size_t)n * 288 + (t - 192)] = s;
}

// res_2d  (unchanged from R6)
__global__ __launch_bounds__(256) void k_v2d(const float* __restrict__ in2d,
    float* __restrict__ ws)
{
    __shared__ float at[12 * 768];
    const int n = blockIdx.x, t = threadIdx.x;
    {
        const float4* a4 = reinterpret_cast<const float4*>(ws + OFF_LG + (size_t)n * 9216);
        float4* l4 = reinterpret_cast<float4*>(at);
        for (int i = t; i < 2304; i += 256) l4[i] = a4[i];
    }
    __syncthreads();
    const int c = t & 127, hg = t >> 7;
    const float* p = in2d + (size_t)n * 768 * 128 + c;
    float acc[6] = {0,0,0,0,0,0};
    for (int m = 0; m < 768; ++m) {
        const float x = p[(size_t)m * 128];
#pragma unroll
        for (int j = 0; j < 6; ++j) acc[j] += at[(hg*6 + j) * 768 + m] * x;
    }
    float* fo = ws + OFF_FIN + (size_t)n * 2112 + 576;
#pragma unroll
    for (int j = 0; j < 6; ++j) fo[(hg*6 + j) * 128 + c] = acc[j];
}

// res_pt_l  (unchanged)
__global__ __launch_bounds__(256) void k_epi(const float* __restrict__ trans,
    float* __restrict__ ws)
{
    const int o = blockIdx.x * 256 + threadIdx.x;
    if (o >= 768 * 288) return;
    const int n = o / 288, q = o - 288 * n, i = q / 96, p = q - 96 * i;
    const float* R = ws + OFF_R + (size_t)n * 9;
    const float* g = ws + OFF_PTG + (size_t)n * 288;
    float s = 0.f;
    for (int j = 0; j < 3; ++j) s += R[j*3 + i] * (g[j*96 + p] - trans[n*3 + j]);
    ws[OFF_FIN + (size_t)n * 2112 + 192 + q] = s;
}

// pt_norm  (unchanged)
__global__ __launch_bounds__(256) void k_norm(float* __restrict__ ws)
{
    const int o = blockIdx.x * 256 + threadIdx.x;
    if (o >= 768 * 96) return;
    const int n = o / 96, p = o - 96 * n;
    const float* f = ws + OFF_FIN + (size_t)n * 2112 + 192;
    const float a = f[p], b = f[96 + p], c = f[192 + p];
    ws[OFF_FIN + (size_t)n * 2112 + 480 + p] = sqrtf(1e-8f + a*a + b*b + c*c);
}

// ---------------------------------------------------------------------------
// Final GEMM v2: both fin tile and wout tile staged in LDS with bulk float4
// loads; inner loop runs entirely from LDS.
// ---------------------------------------------------------------------------
__global__ __launch_bounds__(256) void k_final(const float* __restrict__ wout,
    const float* __restrict__ bout, const float* __restrict__ ws,
    float* __restrict__ out)
{
    __shared__ float At[8][64];
    __shared__ float Bt[64][132];
    const float* fin = ws + OFF_FIN;
    const int r0 = blockIdx.y * 8;
    const int c0 = blockIdx.x * 128;
    const int t = threadIdx.x;
    const int c = t & 127, half = t >> 7;
    float acc[4] = {0.f, 0.f, 0.f, 0.f};
    for (int k0 = 0; k0 < 2112; k0 += 64) {
        __syncthreads();
        if (t < 128) {   // At: 8 rows x 16 float4
            const int r = t >> 4, j = t & 15;
            *reinterpret_cast<float4*>(&At[r][j * 4]) =
                *reinterpret_cast<const float4*>(&fin[(size_t)(r0 + r) * 2112 + k0 + j * 4]);
        }
#pragma unroll
        for (int i = t; i < 2048; i += 256) {  // Bt: 64 rows x 32 float4
            const int k = i >> 5, j = i & 31;
            *reinterpret_cast<float4*>(&Bt[k][j * 4]) =
                *reinterpret_cast<const float4*>(&wout[(size_t)(k0 + k) * 384 + c0 + j * 4]);
        }
        __syncthreads();
#pragma unroll
        for (int k = 0; k < 64; ++k) {
            const float b = Bt[k][c];
#pragma unroll
            for (int r = 0; r < 4; ++r) acc[r] += At[half*4 + r][k] * b;
        }
    }
#pragma unroll
    for (int r = 0; r < 4; ++r)
        out[(size_t)(r0 + half*4 + r) * 384 + c0 + c] = acc[r] + bout[c0 + c];
}

// ---------------------------------------------------------------------------
extern "C" void kernel_launch(void* const* d_in, const int* in_sizes, int n_in,
                              void* d_out, int out_size, void* d_ws, size_t ws_size,
                              hipStream_t stream)
{
    const float* in1d  = (const float*)d_in[0];
    const float* in2d  = (const float*)d_in[1];
    const float* maskp = (const float*)d_in[2];
    const float* quat  = (const float*)d_in[3];
    const float* trans = (const float*)d_in[4];
    const float* wq    = (const float*)d_in[5];
    const float* bq    = (const float*)d_in[6];
    const float* wkv   = (const float*)d_in[7];
    const float* bkv   = (const float*)d_in[8];
    const float* wqp   = (const float*)d_in[9];
    const float* bqp   = (const float*)d_in[10];
    const float* wkvp  = (const float*)d_in[11];
    const float* bkvp  = (const float*)d_in[12];
    const float* pwr   = (const float*)d_in[13];
    const float* w2d   = (const float*)d_in[14];
    const float* b2d   = (const float*)d_in[15];
    const float* wout  = (const float*)d_in[16];
    const float* bout  = (const float*)d_in[17];
    float* ws  = (float*)d_ws;
    float* out = (float*)d_out;

    if (ws_size < WS_TOTAL * sizeof(float)) {
        const float val = 1000.0f + (float)(ws_size / (1024.0 * 1024.0));
        k_sentinel<<<dim3((out_size + 255) / 256), dim3(256), 0, stream>>>(out, out_size, val);
        return;
    }

    dim3 blk(256);
    k_proj<<<dim3(1, 96), blk, 0, stream>>>(in1d, wq,   bq,   ws, 192, 0);
    k_proj<<<dim3(2, 96), blk, 0, stream>>>(in1d, wkv,  bkv,  ws, 384, 192);
    k_proj<<<dim3(1, 96), blk, 0, stream>>>(in1d, wqp,  bqp,  ws, 144, 576);
    k_proj<<<dim3(2, 96), blk, 0, stream>>>(in1d, wkvp, bkvp, ws, 432, 720);
    k_rmat<<<dim3((768*9 + 255)/256), blk, 0, stream>>>(quat, ws);
    k_rigid<<<dim3((768*576 + 255)/256), blk, 0, stream>>>(trans, ws);
    k_vcat<<<dim3((768*480 + 255)/256), blk, 0, stream>>>(ws);
    k_logits<<<dim3((768*12*768 + 255)/256), blk, 0, stream>>>(maskp, pwr, ws);
    k_a2d<<<dim3(768, 6), blk, 0, stream>>>(in2d, w2d, b2d, ws);
    k_softmax<<<dim3(2304), blk, 0, stream>>>(ws);
    k_vsp<<<dim3(768), dim3(512), 0, stream>>>(ws);
    k_v2d<<<dim3(768), blk, 0, stream>>>(in2d, ws);
    k_epi<<<dim3((768*288 + 255)/256), blk, 0, stream>>>(trans, ws);
    k_norm<<<dim3((768*96 + 255)/256), blk, 0, stream>>>(ws);
    k_final<<<dim3(3, 96), blk, 0, stream>>>(wout, bout, ws, out);
}

// Round 8
// 1046.297 us; speedup vs baseline: 1.3319x; 1.0674x over previous
//
#include <hip/hip_runtime.h>
#include <cstdint>
#include <cstddef>

// B=1, N=768, CM=384, CP=128, H=12, SQK=SV=16, PQK=4, PV=8, NFIN=2112, NOUT=384
static constexpr float SCALAR_W = 0.14433756729740643f;  // 1/sqrt(3*16)
static constexpr float PTW_C    = 0.13608276348795434f;  // sqrt(1/(3*4*4.5))
static constexpr float RSQRT3   = 0.5773502691896258f;
static constexpr float FP16HUGE = 65504.0f;

// ws layout (floats)
static constexpr size_t OFF_P    = 0;          // 768*1152  [n][ q(192) | kv(384) | qp(144) | kvp(432) ]
static constexpr size_t OFF_R    = 884736;     // 768*9     [n][i*3+j]
static constexpr size_t OFF_QPG  = 891648;     // 768*144   [n][i*48 + h*4 + a]
static constexpr size_t OFF_KVPG = 1002240;    // 768*432   [n][i*144 + h*12 + e]
static constexpr size_t OFF_LG   = 1334016;    // 768*12*768  [n][h][m]  logits -> attn in place
static constexpr size_t OFF_PTG  = 8411904;    // 768*288   [n][i*96 + h*8 + c]  res_pt_g
static constexpr size_t OFF_FIN  = 8633088;    // 768*2112
static constexpr size_t OFF_VCAT = 10255104;   // 768*480   [m][ v_s(192) | vp_g(288) ]
static constexpr size_t OFF_KST  = 10623744;   // 12*16*768 [h][k][m]  k_s transposed
static constexpr size_t OFF_KPT  = 10771200;   // 12*12*768 [h][d][m]  kp_g transposed
static constexpr size_t WS_TOTAL = 10881792;   // floats = 43.5 MB

__global__ void k_sentinel(float* __restrict__ out, int nel, float val)
{
    const int i = blockIdx.x * 256 + threadIdx.x;
    if (i < nel) out[i] = val;
}

// ---------------------------------------------------------------------------
// Tiled projection (unchanged)
// ---------------------------------------------------------------------------
__global__ __launch_bounds__(256) void k_proj(const float* __restrict__ A,
    const float* __restrict__ Bm, const float* __restrict__ bias,
    float* __restrict__ P, int ncols, int colbase)
{
    __shared__ float At[8][384];
    const int t = threadIdx.x;
    const int r0 = blockIdx.y * 8;
    const float4* A4 = reinterpret_cast<const float4*>(A + (size_t)r0 * 384);
    float4* At4 = reinterpret_cast<float4*>(&At[0][0]);
#pragma unroll
    for (int i = 0; i < 3; ++i) At4[t + 256 * i] = A4[t + 256 * i];
    __syncthreads();
    const int col = blockIdx.x * 256 + t;
    if (col >= ncols) return;
    float acc[8] = {0.f,0.f,0.f,0.f,0.f,0.f,0.f,0.f};
    const float* bp = Bm + col;
#pragma unroll 4
    for (int k = 0; k < 384; ++k) {
        const float b = bp[(size_t)k * ncols];
#pragma unroll
        for (int r = 0; r < 8; ++r) acc[r] += At[r][k] * b;
    }
    const float bb = bias[col];
#pragma unroll
    for (int r = 0; r < 8; ++r)
        P[(size_t)(r0 + r) * 1152 + colbase + col] = acc[r] + bb;
}

// R[n][i][j]  (unchanged)
__global__ __launch_bounds__(256) void k_rmat(const float* __restrict__ quat,
    float* __restrict__ ws)
{
    const int o = blockIdx.x * 256 + threadIdx.x;
    if (o >= 768 * 9) return;
    const int n = o / 9, e = o - 9 * n;
    const float q0 = quat[n*4+0], q1 = quat[n*4+1], q2 = quat[n*4+2], q3 = quat[n*4+3];
    const float inv = 1.0f / sqrtf(q0*q0 + q1*q1 + q2*q2 + q3*q3);
    const float w = q0*inv, x = q1*inv, y = q2*inv, z = q3*inv;
    float R[9];
    R[0] = 1.f - 2.f*(y*y + z*z); R[1] = 2.f*(x*y - w*z); R[2] = 2.f*(x*z + w*y);
    R[3] = 2.f*(x*y + w*z); R[4] = 1.f - 2.f*(x*x + z*z); R[5] = 2.f*(y*z - w*x);
    R[6] = 2.f*(x*z - w*y); R[7] = 2.f*(y*z + w*x); R[8] = 1.f - 2.f*(x*x + y*y);
    ws[OFF_R + o] = R[e];
}

// qp_g / kvp_g  (unchanged)
__global__ __launch_bounds__(256) void k_rigid(const float* __restrict__ trans,
    float* __restrict__ ws)
{
    const int o = blockIdx.x * 256 + threadIdx.x;
    if (o >= 768 * 576) return;
    const int n = o / 576, e = o - 576 * n;
    const float* R = ws + OFF_R + (size_t)n * 9;
    if (e < 144) {
        const int i = e / 48, p = e - 48 * i;
        const float* Pn = ws + OFF_P + (size_t)n * 1152 + 576;
        ws[OFF_QPG + (size_t)n*144 + e] =
            R[i*3+0]*Pn[p] + R[i*3+1]*Pn[48+p] + R[i*3+2]*Pn[96+p] + trans[n*3+i];
    } else {
        const int e2 = e - 144;
        const int i = e2 / 144, p = e2 - 144 * i;
        const float* Pn = ws + OFF_P + (size_t)n * 1152 + 720;
        ws[OFF_KVPG + (size_t)n*432 + e2] =
            R[i*3+0]*Pn[p] + R[i*3+1]*Pn[144+p] + R[i*3+2]*Pn[288+p] + trans[n*3+i];
    }
}

// VCAT[m][480]  (unchanged)
__global__ __launch_bounds__(256) void k_vcat(float* __restrict__ ws)
{
    const int o = blockIdx.x * 256 + threadIdx.x;
    if (o >= 768 * 480) return;
    const int m = o / 480, q = o - 480 * m;
    float v;
    if (q < 192) {
        const int h = q >> 4, d = q & 15;
        v = ws[OFF_P + (size_t)m*1152 + 192 + h*32 + 16 + d];
    } else {
        const int q2 = q - 192;
        const int i = q2 / 96, r = q2 - 96*i, h = r >> 3, c = r & 7;
        v = ws[OFF_KVPG + (size_t)m*432 + i*144 + h*12 + 4 + c];
    }
    ws[OFF_VCAT + o] = v;
}

// ---------------------------------------------------------------------------
// NEW: transpose k-side operands to m-contiguous layouts.
// KST[(h*16+k)*768+m] = k_s[m,h,k];  KPT[(h*12+d)*768+m] = kp_g[m,i,h,a], d=i*4+a
// ---------------------------------------------------------------------------
__global__ __launch_bounds__(256) void k_kt(float* __restrict__ ws)
{
    const int o = blockIdx.x * 256 + threadIdx.x;
    if (o >= 768 * 336) return;
    const int m = o / 336, q = o - 336 * m;
    if (q < 192) {
        const int h = q >> 4, k = q & 15;
        ws[OFF_KST + (size_t)(h*16 + k)*768 + m] =
            ws[OFF_P + (size_t)m*1152 + 192 + h*32 + k];
    } else {
        const int d2 = q - 192;
        const int h = d2 / 12, d = d2 - 12 * h;
        const int i = d >> 2, a = d & 3;
        ws[OFF_KPT + (size_t)(h*12 + d)*768 + m] =
            ws[OFF_KVPG + (size_t)m*432 + i*144 + h*12 + a];
    }
}

// ---------------------------------------------------------------------------
// logits v2: grid (n, h); k-side reads fully coalesced via KST/KPT.
// Math identical to R5 version: sc - 0.5*pw*Σ(q-k)^2 - pen.
// ---------------------------------------------------------------------------
__global__ __launch_bounds__(256) void k_logits(const float* __restrict__ maskp,
    const float* __restrict__ pw_raw, float* __restrict__ ws)
{
    __shared__ float qs16[16], qp12[12];
    const int n = blockIdx.x, h = blockIdx.y, t = threadIdx.x;
    if (t < 16) qs16[t] = ws[OFF_P + (size_t)n*1152 + h*16 + t] * SCALAR_W;
    if (t < 12) {
        const int i = t >> 2, a = t & 3;
        qp12[t] = ws[OFF_QPG + (size_t)n*144 + i*48 + h*4 + a];
    }
    __syncthreads();
    const float pw = PTW_C * logf(1.f + expf(pw_raw[h]));
    const float mask_n = maskp[n];
    const float* kst = ws + OFF_KST + (size_t)(h*16)*768;
    const float* kpt = ws + OFF_KPT + (size_t)(h*12)*768;
    float* lg = ws + OFF_LG + ((size_t)n * 12 + h) * 768;
#pragma unroll
    for (int mi = 0; mi < 3; ++mi) {
        const int m = t + mi * 256;
        float sc = 0.f;
#pragma unroll
        for (int k = 0; k < 16; ++k) sc += qs16[k] * kst[(size_t)k*768 + m];
        float d2 = 0.f;
#pragma unroll
        for (int d = 0; d < 12; ++d) {
            const float dq = qp12[d] - kpt[(size_t)d*768 + m];
            d2 += dq * dq;
        }
        const float pen = FP16HUGE * (1.f - mask_n * maskp[m]);
        lg[m] = sc - 0.5f * pw * d2 - pen;
    }
}

// a2d  (unchanged)
__global__ __launch_bounds__(256) void k_a2d(const float* __restrict__ in2d,
    const float* __restrict__ w2d, const float* __restrict__ b2d,
    float* __restrict__ ws)
{
    __shared__ float w2l[1536];
    const int n = blockIdx.x, mt = blockIdx.y, t = threadIdx.x;
    for (int i = t; i < 1536; i += 256) w2l[i] = w2d[i];
    __syncthreads();
    const int cg = t & 3, pr = t >> 2;
#pragma unroll
    for (int half = 0; half < 2; ++half) {
        const int m = mt * 128 + half * 64 + pr;
        const float* p = in2d + ((size_t)n * 768 + m) * 128 + cg * 32;
        float acc[12] = {0,0,0,0,0,0,0,0,0,0,0,0};
#pragma unroll
        for (int cq = 0; cq < 8; ++cq) {
            const float4 v = *reinterpret_cast<const float4*>(p + cq * 4);
#pragma unroll
            for (int j = 0; j < 4; ++j) {
                const float x = (&v.x)[j];
                const int c = cg * 32 + cq * 4 + j;
#pragma unroll
                for (int h = 0; h < 12; ++h) acc[h] += x * w2l[c * 12 + h];
            }
        }
#pragma unroll
        for (int h = 0; h < 12; ++h) {
            acc[h] += __shfl_xor(acc[h], 1);
            acc[h] += __shfl_xor(acc[h], 2);
        }
        if (cg == 0) {
            float* lgp = ws + OFF_LG + ((size_t)n * 12) * 768 + m;
#pragma unroll
            for (int h = 0; h < 12; ++h)
                lgp[(size_t)h * 768] += (acc[h] + b2d[h]) * RSQRT3;
        }
    }
}

// softmax  (unchanged)
__global__ __launch_bounds__(256) void k_softmax(float* __restrict__ ws)
{
    const int wid = (blockIdx.x * 256 + threadIdx.x) >> 6;
    const int lane = threadIdx.x & 63;
    if (wid >= 768 * 12) return;
    float* lg = ws + OFF_LG + (size_t)wid * 768;
    float v[12];
    float mx = -3.0e38f;
#pragma unroll
    for (int i = 0; i < 12; ++i) { v[i] = lg[lane + i*64]; mx = fmaxf(mx, v[i]); }
#pragma unroll
    for (int off = 32; off > 0; off >>= 1) mx = fmaxf(mx, __shfl_xor(mx, off));
    float s = 0.f;
#pragma unroll
    for (int i = 0; i < 12; ++i) { v[i] = expf(v[i] - mx); s += v[i]; }
#pragma unroll
    for (int off = 32; off > 0; off >>= 1) s += __shfl_xor(s, off);
    const float inv = 1.f / s;
#pragma unroll
    for (int i = 0; i < 12; ++i) lg[lane + i*64] = v[i] * inv;
}

// k_vsp  (unchanged)
__global__ __launch_bounds__(512) void k_vsp(float* __restrict__ ws)
{
    __shared__ float at[12][776];
    const int n = blockIdx.x, t = threadIdx.x;
    {
        const float4* a4 = reinterpret_cast<const float4*>(ws + OFF_LG + (size_t)n * 9216);
        for (int i = t; i < 2304; i += 512) {
            const int row = i / 192, j = i - row * 192;
            *reinterpret_cast<float4*>(&at[row][j * 4]) = a4[i];
        }
    }
    __syncthreads();
    if (t >= 480) return;
    int h;
    if (t < 192) h = t >> 4;
    else { const int r = (t - 192) % 96; h = r >> 3; }
    const float* v = ws + OFF_VCAT + t;
    const float* a = &at[h][0];
    float s = 0.f;
    for (int m = 0; m < 768; ++m) s += a[m] * v[(size_t)m * 480];
    if (t < 192) ws[OFF_FIN + (size_t)n * 2112 + t] = s;
    else         ws[OFF_PTG + (size_t)n * 288 + (t - 192)] = s;
}

// res_2d  (unchanged)
__global__ __launch_bounds__(256) void k_v2d(const float* __restrict__ in2d,
    float* __restrict__ ws)
{
    __shared__ float at[12 * 768];
    const int n = blockIdx.x, t = threadIdx.x;
    {
        const float4* a4 = reinterpret_cast<const float4*>(ws + OFF_LG + (size_t)n * 9216);
        float4* l4 = reinterpret_cast<float4*>(at);
        for (int i = t; i < 2304; i += 256) l4[i] = a4[i];
    }
    __syncthreads();
    const int c = t & 127, hg = t >> 7;
    const float* p = in2d + (size_t)n * 768 * 128 + c;
    float acc[6] = {0,0,0,0,0,0};
    for (int m = 0; m < 768; ++m) {
        const float x = p[(size_t)m * 128];
#pragma unroll
        for (int j = 0; j < 6; ++j) acc[j] += at[(hg*6 + j) * 768 + m] * x;
    }
    float* fo = ws + OFF_FIN + (size_t)n * 2112 + 576;
#pragma unroll
    for (int j = 0; j < 6; ++j) fo[(hg*6 + j) * 128 + c] = acc[j];
}

// res_pt_l  (unchanged)
__global__ __launch_bounds__(256) void k_epi(const float* __restrict__ trans,
    float* __restrict__ ws)
{
    const int o = blockIdx.x * 256 + threadIdx.x;
    if (o >= 768 * 288) return;
    const int n = o / 288, q = o - 288 * n, i = q / 96, p = q - 96 * i;
    const float* R = ws + OFF_R + (size_t)n * 9;
    const float* g = ws + OFF_PTG + (size_t)n * 288;
    float s = 0.f;
    for (int j = 0; j < 3; ++j) s += R[j*3 + i] * (g[j*96 + p] - trans[n*3 + j]);
    ws[OFF_FIN + (size_t)n * 2112 + 192 + q] = s;
}

// pt_norm  (unchanged)
__global__ __launch_bounds__(256) void k_norm(float* __restrict__ ws)
{
    const int o = blockIdx.x * 256 + threadIdx.x;
    if (o >= 768 * 96) return;
    const int n = o / 96, p = o - 96 * n;
    const float* f = ws + OFF_FIN + (size_t)n * 2112 + 192;
    const float a = f[p], b = f[96 + p], c = f[192 + p];
    ws[OFF_FIN + (size_t)n * 2112 + 480 + p] = sqrtf(1e-8f + a*a + b*b + c*c);
}

// Final GEMM v2  (unchanged)
__global__ __launch_bounds__(256) void k_final(const float* __restrict__ wout,
    const float* __restrict__ bout, const float* __restrict__ ws,
    float* __restrict__ out)
{
    __shared__ float At[8][64];
    __shared__ float Bt[64][132];
    const float* fin = ws + OFF_FIN;
    const int r0 = blockIdx.y * 8;
    const int c0 = blockIdx.x * 128;
    const int t = threadIdx.x;
    const int c = t & 127, half = t >> 7;
    float acc[4] = {0.f, 0.f, 0.f, 0.f};
    for (int k0 = 0; k0 < 2112; k0 += 64) {
        __syncthreads();
        if (t < 128) {
            const int r = t >> 4, j = t & 15;
            *reinterpret_cast<float4*>(&At[r][j * 4]) =
                *reinterpret_cast<const float4*>(&fin[(size_t)(r0 + r) * 2112 + k0 + j * 4]);
        }
#pragma unroll
        for (int i = t; i < 2048; i += 256) {
            const int k = i >> 5, j = i & 31;
            *reinterpret_cast<float4*>(&Bt[k][j * 4]) =
                *reinterpret_cast<const float4*>(&wout[(size_t)(k0 + k) * 384 + c0 + j * 4]);
        }
        __syncthreads();
#pragma unroll
        for (int k = 0; k < 64; ++k) {
            const float b = Bt[k][c];
#pragma unroll
            for (int r = 0; r < 4; ++r) acc[r] += At[half*4 + r][k] * b;
        }
    }
#pragma unroll
    for (int r = 0; r < 4; ++r)
        out[(size_t)(r0 + half*4 + r) * 384 + c0 + c] = acc[r] + bout[c0 + c];
}

// ---------------------------------------------------------------------------
extern "C" void kernel_launch(void* const* d_in, const int* in_sizes, int n_in,
                              void* d_out, int out_size, void* d_ws, size_t ws_size,
                              hipStream_t stream)
{
    const float* in1d  = (const float*)d_in[0];
    const float* in2d  = (const float*)d_in[1];
    const float* maskp = (const float*)d_in[2];
    const float* quat  = (const float*)d_in[3];
    const float* trans = (const float*)d_in[4];
    const float* wq    = (const float*)d_in[5];
    const float* bq    = (const float*)d_in[6];
    const float* wkv   = (const float*)d_in[7];
    const float* bkv   = (const float*)d_in[8];
    const float* wqp   = (const float*)d_in[9];
    const float* bqp   = (const float*)d_in[10];
    const float* wkvp  = (const float*)d_in[11];
    const float* bkvp  = (const float*)d_in[12];
    const float* pwr   = (const float*)d_in[13];
    const float* w2d   = (const float*)d_in[14];
    const float* b2d   = (const float*)d_in[15];
    const float* wout  = (const float*)d_in[16];
    const float* bout  = (const float*)d_in[17];
    float* ws  = (float*)d_ws;
    float* out = (float*)d_out;

    if (ws_size < WS_TOTAL * sizeof(float)) {
        const float val = 1000.0f + (float)(ws_size / (1024.0 * 1024.0));
        k_sentinel<<<dim3((out_size + 255) / 256), dim3(256), 0, stream>>>(out, out_size, val);
        return;
    }

    dim3 blk(256);
    k_proj<<<dim3(1, 96), blk, 0, stream>>>(in1d, wq,   bq,   ws, 192, 0);
    k_proj<<<dim3(2, 96), blk, 0, stream>>>(in1d, wkv,  bkv,  ws, 384, 192);
    k_proj<<<dim3(1, 96), blk, 0, stream>>>(in1d, wqp,  bqp,  ws, 144, 576);
    k_proj<<<dim3(2, 96), blk, 0, stream>>>(in1d, wkvp, bkvp, ws, 432, 720);
    k_rmat<<<dim3((768*9 + 255)/256), blk, 0, stream>>>(quat, ws);
    k_rigid<<<dim3((768*576 + 255)/256), blk, 0, stream>>>(trans, ws);
    k_vcat<<<dim3((768*480 + 255)/256), blk, 0, stream>>>(ws);
    k_kt<<<dim3((768*336 + 255)/256), blk, 0, stream>>>(ws);
    k_logits<<<dim3(768, 12), blk, 0, stream>>>(maskp, pwr, ws);
    k_a2d<<<dim3(768, 6), blk, 0, stream>>>(in2d, w2d, b2d, ws);
    k_softmax<<<dim3(2304), blk, 0, stream>>>(ws);
    k_vsp<<<dim3(768), dim3(512), 0, stream>>>(ws);
    k_v2d<<<dim3(768), blk, 0, stream>>>(in2d, ws);
    k_epi<<<dim3((768*288 + 255)/256), blk, 0, stream>>>(trans, ws);
    k_norm<<<dim3((768*96 + 255)/256), blk, 0, stream>>>(ws);
    k_final<<<dim3(3, 96), blk, 0, stream>>>(wout, bout, ws, out);
}

// Round 9
// 701.836 us; speedup vs baseline: 1.9856x; 1.4908x over previous
//
#include <hip/hip_runtime.h>
#include <cstdint>
#include <cstddef>

// B=1, N=768, CM=384, CP=128, H=12, SQK=SV=16, PQK=4, PV=8, NFIN=2112, NOUT=384
static constexpr float SCALAR_W = 0.14433756729740643f;  // 1/sqrt(3*16)
static constexpr float PTW_C    = 0.13608276348795434f;  // sqrt(1/(3*4*4.5))
static constexpr float RSQRT3   = 0.5773502691896258f;
static constexpr float FP16HUGE = 65504.0f;

// ws layout (floats)
static constexpr size_t OFF_P    = 0;          // 768*1152  [n][ q(192) | kv(384) | qp(144) | kvp(432) ]
static constexpr size_t OFF_R    = 884736;     // 768*9     [n][i*3+j]
static constexpr size_t OFF_QPG  = 891648;     // 768*144   [n][i*48 + h*4 + a]
static constexpr size_t OFF_KVPG = 1002240;    // 768*432   [n][i*144 + h*12 + e]
static constexpr size_t OFF_LG   = 1334016;    // 768*12*768  [n][h][m]  logits -> attn in place
static constexpr size_t OFF_PTG  = 8411904;    // 768*288   [n][i*96 + h*8 + c]  res_pt_g
static constexpr size_t OFF_FIN  = 8633088;    // 768*2112
static constexpr size_t OFF_VCAT = 10255104;   // 768*480   [m][ v_s(192) | vp_g(288) ]
static constexpr size_t OFF_KST  = 10623744;   // 12*16*768 [h][k][m]  k_s transposed
static constexpr size_t OFF_KPT  = 10771200;   // 12*12*768 [h][d][m]  kp_g transposed
static constexpr size_t WS_TOTAL = 10881792;   // floats = 43.5 MB

__global__ void k_sentinel(float* __restrict__ out, int nel, float val)
{
    const int i = blockIdx.x * 256 + threadIdx.x;
    if (i < nel) out[i] = val;
}

// ---------------------------------------------------------------------------
// Tiled projection v2: 16 rows of A staged in LDS; 256 threads over cols.
// ---------------------------------------------------------------------------
__global__ __launch_bounds__(256) void k_proj(const float* __restrict__ A,
    const float* __restrict__ Bm, const float* __restrict__ bias,
    float* __restrict__ P, int ncols, int colbase)
{
    __shared__ float At[16][384];
    const int t = threadIdx.x;
    const int r0 = blockIdx.y * 16;
    const float4* A4 = reinterpret_cast<const float4*>(A + (size_t)r0 * 384);
    float4* At4 = reinterpret_cast<float4*>(&At[0][0]);
#pragma unroll
    for (int i = 0; i < 6; ++i) At4[t + 256 * i] = A4[t + 256 * i];  // 1536 float4
    __syncthreads();
    const int col = blockIdx.x * 256 + t;
    if (col >= ncols) return;
    float acc[16];
#pragma unroll
    for (int r = 0; r < 16; ++r) acc[r] = 0.f;
    const float* bp = Bm + col;
#pragma unroll 2
    for (int k = 0; k < 384; ++k) {
        const float b = bp[(size_t)k * ncols];
#pragma unroll
        for (int r = 0; r < 16; ++r) acc[r] += At[r][k] * b;
    }
    const float bb = bias[col];
#pragma unroll
    for (int r = 0; r < 16; ++r)
        P[(size_t)(r0 + r) * 1152 + colbase + col] = acc[r] + bb;
}

// R[n][i][j]  (unchanged)
__global__ __launch_bounds__(256) void k_rmat(const float* __restrict__ quat,
    float* __restrict__ ws)
{
    const int o = blockIdx.x * 256 + threadIdx.x;
    if (o >= 768 * 9) return;
    const int n = o / 9, e = o - 9 * n;
    const float q0 = quat[n*4+0], q1 = quat[n*4+1], q2 = quat[n*4+2], q3 = quat[n*4+3];
    const float inv = 1.0f / sqrtf(q0*q0 + q1*q1 + q2*q2 + q3*q3);
    const float w = q0*inv, x = q1*inv, y = q2*inv, z = q3*inv;
    float R[9];
    R[0] = 1.f - 2.f*(y*y + z*z); R[1] = 2.f*(x*y - w*z); R[2] = 2.f*(x*z + w*y);
    R[3] = 2.f*(x*y + w*z); R[4] = 1.f - 2.f*(x*x + z*z); R[5] = 2.f*(y*z - w*x);
    R[6] = 2.f*(x*z - w*y); R[7] = 2.f*(y*z + w*x); R[8] = 1.f - 2.f*(x*x + y*y);
    ws[OFF_R + o] = R[e];
}

// qp_g / kvp_g  (unchanged)
__global__ __launch_bounds__(256) void k_rigid(const float* __restrict__ trans,
    float* __restrict__ ws)
{
    const int o = blockIdx.x * 256 + threadIdx.x;
    if (o >= 768 * 576) return;
    const int n = o / 576, e = o - 576 * n;
    const float* R = ws + OFF_R + (size_t)n * 9;
    if (e < 144) {
        const int i = e / 48, p = e - 48 * i;
        const float* Pn = ws + OFF_P + (size_t)n * 1152 + 576;
        ws[OFF_QPG + (size_t)n*144 + e] =
            R[i*3+0]*Pn[p] + R[i*3+1]*Pn[48+p] + R[i*3+2]*Pn[96+p] + trans[n*3+i];
    } else {
        const int e2 = e - 144;
        const int i = e2 / 144, p = e2 - 144 * i;
        const float* Pn = ws + OFF_P + (size_t)n * 1152 + 720;
        ws[OFF_KVPG + (size_t)n*432 + e2] =
            R[i*3+0]*Pn[p] + R[i*3+1]*Pn[144+p] + R[i*3+2]*Pn[288+p] + trans[n*3+i];
    }
}

// VCAT[m][480]  (unchanged)
__global__ __launch_bounds__(256) void k_vcat(float* __restrict__ ws)
{
    const int o = blockIdx.x * 256 + threadIdx.x;
    if (o >= 768 * 480) return;
    const int m = o / 480, q = o - 480 * m;
    float v;
    if (q < 192) {
        const int h = q >> 4, d = q & 15;
        v = ws[OFF_P + (size_t)m*1152 + 192 + h*32 + 16 + d];
    } else {
        const int q2 = q - 192;
        const int i = q2 / 96, r = q2 - 96*i, h = r >> 3, c = r & 7;
        v = ws[OFF_KVPG + (size_t)m*432 + i*144 + h*12 + 4 + c];
    }
    ws[OFF_VCAT + o] = v;
}

// k-side transposes  (unchanged)
__global__ __launch_bounds__(256) void k_kt(float* __restrict__ ws)
{
    const int o = blockIdx.x * 256 + threadIdx.x;
    if (o >= 768 * 336) return;
    const int m = o / 336, q = o - 336 * m;
    if (q < 192) {
        const int h = q >> 4, k = q & 15;
        ws[OFF_KST + (size_t)(h*16 + k)*768 + m] =
            ws[OFF_P + (size_t)m*1152 + 192 + h*32 + k];
    } else {
        const int d2 = q - 192;
        const int h = d2 / 12, d = d2 - 12 * h;
        const int i = d >> 2, a = d & 3;
        ws[OFF_KPT + (size_t)(h*12 + d)*768 + m] =
            ws[OFF_KVPG + (size_t)m*432 + i*144 + h*12 + a];
    }
}

// ---------------------------------------------------------------------------
// FUSED logits + a2d: grid (n, 6 m-tiles of 128). Phase A computes a2d for
// the tile into LDS (quad scheme, identical math to old k_a2d). Phase B
// computes sc + pt - pen + a2d and writes LG once (no RMW).
// ---------------------------------------------------------------------------
__global__ __launch_bounds__(256) void k_lga(const float* __restrict__ in2d,
    const float* __restrict__ w2d, const float* __restrict__ b2d,
    const float* __restrict__ maskp, const float* __restrict__ pw_raw,
    float* __restrict__ ws)
{
    __shared__ float w2l[1536];
    __shared__ float a2l[12][132];
    __shared__ float qs[192], qpl[144], pwl[12], b2l[12];
    const int n = blockIdx.x, mt = blockIdx.y, t = threadIdx.x;
    if (t < 192) qs[t] = ws[OFF_P + (size_t)n*1152 + t] * SCALAR_W;
    if (t < 144) qpl[t] = ws[OFF_QPG + (size_t)n*144 + t];   // [i*48 + h*4 + a]
    if (t < 12) {
        pwl[t] = PTW_C * logf(1.f + expf(pw_raw[t]));
        b2l[t] = b2d[t];
    }
    for (int i = t; i < 1536; i += 256) w2l[i] = w2d[i];
    const float mask_n = maskp[n];
    __syncthreads();

    // ---- phase A: a2d for 128 m rows (quad scheme) ----
    const int cg = t & 3, pr = t >> 2;
#pragma unroll
    for (int half = 0; half < 2; ++half) {
        const int mm = half * 64 + pr;
        const int m = mt * 128 + mm;
        const float* p = in2d + ((size_t)n * 768 + m) * 128 + cg * 32;
        float acc[12] = {0,0,0,0,0,0,0,0,0,0,0,0};
#pragma unroll
        for (int cq = 0; cq < 8; ++cq) {
            const float4 v = *reinterpret_cast<const float4*>(p + cq * 4);
#pragma unroll
            for (int j = 0; j < 4; ++j) {
                const float x = (&v.x)[j];
                const int c = cg * 32 + cq * 4 + j;
#pragma unroll
                for (int h = 0; h < 12; ++h) acc[h] += x * w2l[c * 12 + h];
            }
        }
#pragma unroll
        for (int h = 0; h < 12; ++h) {
            acc[h] += __shfl_xor(acc[h], 1);
            acc[h] += __shfl_xor(acc[h], 2);
        }
        if (cg == 0) {
#pragma unroll
            for (int h = 0; h < 12; ++h)
                a2l[h][mm] = (acc[h] + b2l[h]) * RSQRT3;
        }
    }
    __syncthreads();

    // ---- phase B: logits; 6 (h,m) outputs per thread ----
    const float* kst = ws + OFF_KST;
    const float* kpt = ws + OFF_KPT;
#pragma unroll
    for (int i = 0; i < 6; ++i) {
        const int idx = i * 256 + t;          // 0..1535
        const int h = idx >> 7, mm = idx & 127;
        const int m = mt * 128 + mm;
        float sc = 0.f;
        const float* ks = kst + (size_t)(h*16)*768 + m;
#pragma unroll
        for (int k = 0; k < 16; ++k) sc += qs[h*16 + k] * ks[(size_t)k*768];
        float d2 = 0.f;
        const float* kp = kpt + (size_t)(h*12)*768 + m;
#pragma unroll
        for (int d = 0; d < 12; ++d) {
            const int ii = d >> 2, a = d & 3;
            const float dq = qpl[ii*48 + h*4 + a] - kp[(size_t)d*768];
            d2 += dq * dq;
        }
        const float pen = FP16HUGE * (1.f - mask_n * maskp[m]);
        ws[OFF_LG + ((size_t)n * 12 + h) * 768 + m] =
            sc - 0.5f * pwl[h] * d2 - pen + a2l[h][mm];
    }
}

// ---------------------------------------------------------------------------
// FUSED softmax + vsp + v2d: one block (512 thr) per query row n.
// Stage LG row, softmax in LDS, then res_2d (in2d stream) and
// res_s/res_pt_g (VCAT stream).
// ---------------------------------------------------------------------------
__global__ __launch_bounds__(512) void k_att(const float* __restrict__ in2d,
    float* __restrict__ ws)
{
    __shared__ float at[12][776];
    const int n = blockIdx.x, t = threadIdx.x;
    const int wv = t >> 6, lane = t & 63;
    {
        const float4* a4 = reinterpret_cast<const float4*>(ws + OFF_LG + (size_t)n * 9216);
        for (int i = t; i < 2304; i += 512) {
            const int row = i / 192, j = i - row * 192;
            *reinterpret_cast<float4*>(&at[row][j * 4]) = a4[i];
        }
    }
    __syncthreads();

    // softmax rows; waves 0..7 handle h = wv, wv+8
    for (int h = wv; h < 12; h += 8) {
        float v[12];
        float mx = -3.0e38f;
#pragma unroll
        for (int i = 0; i < 12; ++i) { v[i] = at[h][lane + i*64]; mx = fmaxf(mx, v[i]); }
#pragma unroll
        for (int off = 32; off > 0; off >>= 1) mx = fmaxf(mx, __shfl_xor(mx, off));
        float s = 0.f;
#pragma unroll
        for (int i = 0; i < 12; ++i) { v[i] = expf(v[i] - mx); s += v[i]; }
#pragma unroll
        for (int off = 32; off > 0; off >>= 1) s += __shfl_xor(s, off);
        const float inv = 1.f / s;
#pragma unroll
        for (int i = 0; i < 12; ++i) at[h][lane + i*64] = v[i] * inv;
    }
    __syncthreads();

    // ---- res_2d: group g = t>>7 owns 3 heads; c = t&127 ----
    {
        const int c = t & 127, g = t >> 7;
        const float* p = in2d + (size_t)n * 768 * 128 + c;
        float a0 = 0.f, a1 = 0.f, a2 = 0.f;
        for (int m = 0; m < 768; ++m) {
            const float x = p[(size_t)m * 128];
            a0 += at[g*3+0][m] * x;
            a1 += at[g*3+1][m] * x;
            a2 += at[g*3+2][m] * x;
        }
        float* fo = ws + OFF_FIN + (size_t)n * 2112 + 576;
        fo[(g*3+0)*128 + c] = a0;
        fo[(g*3+1)*128 + c] = a1;
        fo[(g*3+2)*128 + c] = a2;
    }

    // ---- res_s + res_pt_g via VCAT (threads 0..479) ----
    if (t < 480) {
        int h;
        if (t < 192) h = t >> 4;
        else { const int r = (t - 192) % 96; h = r >> 3; }
        const float* v = ws + OFF_VCAT + t;
        const float* a = &at[h][0];
        float s = 0.f;
        for (int m = 0; m < 768; ++m) s += a[m] * v[(size_t)m * 480];
        if (t < 192) ws[OFF_FIN + (size_t)n * 2112 + t] = s;
        else         ws[OFF_PTG + (size_t)n * 288 + (t - 192)] = s;
    }
}

// res_pt_l  (unchanged)
__global__ __launch_bounds__(256) void k_epi(const float* __restrict__ trans,
    float* __restrict__ ws)
{
    const int o = blockIdx.x * 256 + threadIdx.x;
    if (o >= 768 * 288) return;
    const int n = o / 288, q = o - 288 * n, i = q / 96, p = q - 96 * i;
    const float* R = ws + OFF_R + (size_t)n * 9;
    const float* g = ws + OFF_PTG + (size_t)n * 288;
    float s = 0.f;
    for (int j = 0; j < 3; ++j) s += R[j*3 + i] * (g[j*96 + p] - trans[n*3 + j]);
    ws[OFF_FIN + (size_t)n * 2112 + 192 + q] = s;
}

// pt_norm  (unchanged)
__global__ __launch_bounds__(256) void k_norm(float* __restrict__ ws)
{
    const int o = blockIdx.x * 256 + threadIdx.x;
    if (o >= 768 * 96) return;
    const int n = o / 96, p = o - 96 * n;
    const float* f = ws + OFF_FIN + (size_t)n * 2112 + 192;
    const float a = f[p], b = f[96 + p], c = f[192 + p];
    ws[OFF_FIN + (size_t)n * 2112 + 480 + p] = sqrtf(1e-8f + a*a + b*b + c*c);
}

// Final GEMM v2  (unchanged)
__global__ __launch_bounds__(256) void k_final(const float* __restrict__ wout,
    const float* __restrict__ bout, const float* __restrict__ ws,
    float* __restrict__ out)
{
    __shared__ float At[8][64];
    __shared__ float Bt[64][132];
    const float* fin = ws + OFF_FIN;
    const int r0 = blockIdx.y * 8;
    const int c0 = blockIdx.x * 128;
    const int t = threadIdx.x;
    const int c = t & 127, half = t >> 7;
    float acc[4] = {0.f, 0.f, 0.f, 0.f};
    for (int k0 = 0; k0 < 2112; k0 += 64) {
        __syncthreads();
        if (t < 128) {
            const int r = t >> 4, j = t & 15;
            *reinterpret_cast<float4*>(&At[r][j * 4]) =
                *reinterpret_cast<const float4*>(&fin[(size_t)(r0 + r) * 2112 + k0 + j * 4]);
        }
#pragma unroll
        for (int i = t; i < 2048; i += 256) {
            const int k = i >> 5, j = i & 31;
            *reinterpret_cast<float4*>(&Bt[k][j * 4]) =
                *reinterpret_cast<const float4*>(&wout[(size_t)(k0 + k) * 384 + c0 + j * 4]);
        }
        __syncthreads();
#pragma unroll
        for (int k = 0; k < 64; ++k) {
            const float b = Bt[k][c];
#pragma unroll
            for (int r = 0; r < 4; ++r) acc[r] += At[half*4 + r][k] * b;
        }
    }
#pragma unroll
    for (int r = 0; r < 4; ++r)
        out[(size_t)(r0 + half*4 + r) * 384 + c0 + c] = acc[r] + bout[c0 + c];
}

// ---------------------------------------------------------------------------
extern "C" void kernel_launch(void* const* d_in, const int* in_sizes, int n_in,
                              void* d_out, int out_size, void* d_ws, size_t ws_size,
                              hipStream_t stream)
{
    const float* in1d  = (const float*)d_in[0];
    const float* in2d  = (const float*)d_in[1];
    const float* maskp = (const float*)d_in[2];
    const float* quat  = (const float*)d_in[3];
    const float* trans = (const float*)d_in[4];
    const float* wq    = (const float*)d_in[5];
    const float* bq    = (const float*)d_in[6];
    const float* wkv   = (const float*)d_in[7];
    const float* bkv   = (const float*)d_in[8];
    const float* wqp   = (const float*)d_in[9];
    const float* bqp   = (const float*)d_in[10];
    const float* wkvp  = (const float*)d_in[11];
    const float* bkvp  = (const float*)d_in[12];
    const float* pwr   = (const float*)d_in[13];
    const float* w2d   = (const float*)d_in[14];
    const float* b2d   = (const float*)d_in[15];
    const float* wout  = (const float*)d_in[16];
    const float* bout  = (const float*)d_in[17];
    float* ws  = (float*)d_ws;
    float* out = (float*)d_out;

    if (ws_size < WS_TOTAL * sizeof(float)) {
        const float val = 1000.0f + (float)(ws_size / (1024.0 * 1024.0));
        k_sentinel<<<dim3((out_size + 255) / 256), dim3(256), 0, stream>>>(out, out_size, val);
        return;
    }

    dim3 blk(256);
    k_proj<<<dim3(1, 48), blk, 0, stream>>>(in1d, wq,   bq,   ws, 192, 0);
    k_proj<<<dim3(2, 48), blk, 0, stream>>>(in1d, wkv,  bkv,  ws, 384, 192);
    k_proj<<<dim3(1, 48), blk, 0, stream>>>(in1d, wqp,  bqp,  ws, 144, 576);
    k_proj<<<dim3(2, 48), blk, 0, stream>>>(in1d, wkvp, bkvp, ws, 432, 720);
    k_rmat<<<dim3((768*9 + 255)/256), blk, 0, stream>>>(quat, ws);
    k_rigid<<<dim3((768*576 + 255)/256), blk, 0, stream>>>(trans, ws);
    k_vcat<<<dim3((768*480 + 255)/256), blk, 0, stream>>>(ws);
    k_kt<<<dim3((768*336 + 255)/256), blk, 0, stream>>>(ws);
    k_lga<<<dim3(768, 6), blk, 0, stream>>>(in2d, w2d, b2d, maskp, pwr, ws);
    k_att<<<dim3(768), dim3(512), 0, stream>>>(in2d, ws);
    k_epi<<<dim3((768*288 + 255)/256), blk, 0, stream>>>(trans, ws);
    k_norm<<<dim3((768*96 + 255)/256), blk, 0, stream>>>(ws);
    k_final<<<dim3(3, 96), blk, 0, stream>>>(wout, bout, ws, out);
}

// Round 12
// 525.687 us; speedup vs baseline: 2.6509x; 1.3351x over previous
//
#include <hip/hip_runtime.h>
#include <cstdint>
#include <cstddef>

// B=1, N=768, CM=384, CP=128, H=12, SQK=SV=16, PQK=4, PV=8, NFIN=2112, NOUT=384
static constexpr float SCALAR_W = 0.14433756729740643f;  // 1/sqrt(3*16)
static constexpr float PTW_C    = 0.13608276348795434f;  // sqrt(1/(3*4*4.5))
static constexpr float RSQRT3   = 0.5773502691896258f;
static constexpr float FP16HUGE = 65504.0f;

// ws layout (floats)
static constexpr size_t OFF_P    = 0;          // 768*1152  [n][ q(192) | kv(384) | qp(144) | kvp(432) ]
static constexpr size_t OFF_R    = 884736;     // 768*9     [n][i*3+j]
static constexpr size_t OFF_QPG  = 891648;     // 768*144   [n][i*48 + h*4 + a]
static constexpr size_t OFF_KVPG = 1002240;    // 768*432   [n][i*144 + h*12 + e]
static constexpr size_t OFF_LG   = 1334016;    // 768*12*768  [n][h][m]
static constexpr size_t OFF_FIN  = 8633088;    // 768*2112
static constexpr size_t OFF_VCAT = 10255104;   // 768*480   [m][ v_s(192) | vp_g(288) ]
static constexpr size_t OFF_KST  = 10623744;   // 12*16*768 [h][k][m]
static constexpr size_t OFF_KPT  = 10771200;   // 12*12*768 [h][d][m]
static constexpr size_t WS_TOTAL = 10881792;   // floats = 43.5 MB

__global__ void k_sentinel(float* __restrict__ out, int nel, float val)
{
    const int i = blockIdx.x * 256 + threadIdx.x;
    if (i < nel) out[i] = val;
}

// ---------------------------------------------------------------------------
// All four projections in one launch. grid (2, 96, 4); z selects matrix.
// ---------------------------------------------------------------------------
__global__ __launch_bounds__(256) void k_proj_all(const float* __restrict__ A,
    const float* __restrict__ wq,  const float* __restrict__ bq,
    const float* __restrict__ wkv, const float* __restrict__ bkv,
    const float* __restrict__ wqp, const float* __restrict__ bqp,
    const float* __restrict__ wkvp,const float* __restrict__ bkvp,
    float* __restrict__ P)
{
    const int z = blockIdx.z;
    const float* Bm; const float* bias; int ncols, colbase;
    switch (z) {
        case 0: Bm = wq;   bias = bq;   ncols = 192; colbase = 0;   break;
        case 1: Bm = wkv;  bias = bkv;  ncols = 384; colbase = 192; break;
        case 2: Bm = wqp;  bias = bqp;  ncols = 144; colbase = 576; break;
        default:Bm = wkvp; bias = bkvp; ncols = 432; colbase = 720; break;
    }
    if (blockIdx.x * 256 >= ncols) return;
    __shared__ float At[8][384];
    const int t = threadIdx.x;
    const int r0 = blockIdx.y * 8;
    const float4* A4 = reinterpret_cast<const float4*>(A + (size_t)r0 * 384);
    float4* At4 = reinterpret_cast<float4*>(&At[0][0]);
#pragma unroll
    for (int i = 0; i < 3; ++i) At4[t + 256 * i] = A4[t + 256 * i];
    __syncthreads();
    const int col = blockIdx.x * 256 + t;
    if (col >= ncols) return;
    float acc[8] = {0.f,0.f,0.f,0.f,0.f,0.f,0.f,0.f};
    const float* bp = Bm + col;
#pragma unroll 4
    for (int k = 0; k < 384; ++k) {
        const float b = bp[(size_t)k * ncols];
#pragma unroll
        for (int r = 0; r < 8; ++r) acc[r] += At[r][k] * b;
    }
    const float bb = bias[col];
#pragma unroll
    for (int r = 0; r < 8; ++r)
        P[(size_t)(r0 + r) * 1152 + colbase + col] = acc[r] + bb;
}

// R[n][i][j]  (R9-proven)
__global__ __launch_bounds__(256) void k_rmat(const float* __restrict__ quat,
    float* __restrict__ ws)
{
    const int o = blockIdx.x * 256 + threadIdx.x;
    if (o >= 768 * 9) return;
    const int n = o / 9, e = o - 9 * n;
    const float q0 = quat[n*4+0], q1 = quat[n*4+1], q2 = quat[n*4+2], q3 = quat[n*4+3];
    const float inv = 1.0f / sqrtf(q0*q0 + q1*q1 + q2*q2 + q3*q3);
    const float w = q0*inv, x = q1*inv, y = q2*inv, z = q3*inv;
    float R[9];
    R[0] = 1.f - 2.f*(y*y + z*z); R[1] = 2.f*(x*y - w*z); R[2] = 2.f*(x*z + w*y);
    R[3] = 2.f*(x*y + w*z); R[4] = 1.f - 2.f*(x*x + z*z); R[5] = 2.f*(y*z - w*x);
    R[6] = 2.f*(x*z - w*y); R[7] = 2.f*(y*z + w*x); R[8] = 1.f - 2.f*(x*x + y*y);
    ws[OFF_R + o] = R[e];
}

// qp_g / kvp_g  (R9-proven)
__global__ __launch_bounds__(256) void k_rigid(const float* __restrict__ trans,
    float* __restrict__ ws)
{
    const int o = blockIdx.x * 256 + threadIdx.x;
    if (o >= 768 * 576) return;
    const int n = o / 576, e = o - 576 * n;
    const float* R = ws + OFF_R + (size_t)n * 9;
    if (e < 144) {
        const int i = e / 48, p = e - 48 * i;
        const float* Pn = ws + OFF_P + (size_t)n * 1152 + 576;
        ws[OFF_QPG + (size_t)n*144 + e] =
            R[i*3+0]*Pn[p] + R[i*3+1]*Pn[48+p] + R[i*3+2]*Pn[96+p] + trans[n*3+i];
    } else {
        const int e2 = e - 144;
        const int i = e2 / 144, p = e2 - 144 * i;
        const float* Pn = ws + OFF_P + (size_t)n * 1152 + 720;
        ws[OFF_KVPG + (size_t)n*432 + e2] =
            R[i*3+0]*Pn[p] + R[i*3+1]*Pn[144+p] + R[i*3+2]*Pn[288+p] + trans[n*3+i];
    }
}

// VCAT[m][480]  (R9-proven)
__global__ __launch_bounds__(256) void k_vcat(float* __restrict__ ws)
{
    const int o = blockIdx.x * 256 + threadIdx.x;
    if (o >= 768 * 480) return;
    const int m = o / 480, q = o - 480 * m;
    float v;
    if (q < 192) {
        const int h = q >> 4, d = q & 15;
        v = ws[OFF_P + (size_t)m*1152 + 192 + h*32 + 16 + d];
    } else {
        const int q2 = q - 192;
        const int i = q2 / 96, r = q2 - 96*i, h = r >> 3, c = r & 7;
        v = ws[OFF_KVPG + (size_t)m*432 + i*144 + h*12 + 4 + c];
    }
    ws[OFF_VCAT + o] = v;
}

// k-side transposes  (R9-proven)
__global__ __launch_bounds__(256) void k_kt(float* __restrict__ ws)
{
    const int o = blockIdx.x * 256 + threadIdx.x;
    if (o >= 768 * 336) return;
    const int m = o / 336, q = o - 336 * m;
    if (q < 192) {
        const int h = q >> 4, k = q & 15;
        ws[OFF_KST + (size_t)(h*16 + k)*768 + m] =
            ws[OFF_P + (size_t)m*1152 + 192 + h*32 + k];
    } else {
        const int d2 = q - 192;
        const int h = d2 / 12, d = d2 - 12 * h;
        const int i = d >> 2, a = d & 3;
        ws[OFF_KPT + (size_t)(h*12 + d)*768 + m] =
            ws[OFF_KVPG + (size_t)m*432 + i*144 + h*12 + a];
    }
}

// ---------------------------------------------------------------------------
// FUSED logits + a2d  (R9-proven, unchanged)
// ---------------------------------------------------------------------------
__global__ __launch_bounds__(256) void k_lga(const float* __restrict__ in2d,
    const float* __restrict__ w2d, const float* __restrict__ b2d,
    const float* __restrict__ maskp, const float* __restrict__ pw_raw,
    float* __restrict__ ws)
{
    __shared__ float w2l[1536];
    __shared__ float a2l[12][132];
    __shared__ float qs[192], qpl[144], pwl[12], b2l[12];
    const int n = blockIdx.x, mt = blockIdx.y, t = threadIdx.x;
    if (t < 192) qs[t] = ws[OFF_P + (size_t)n*1152 + t] * SCALAR_W;
    if (t < 144) qpl[t] = ws[OFF_QPG + (size_t)n*144 + t];
    if (t < 12) {
        pwl[t] = PTW_C * logf(1.f + expf(pw_raw[t]));
        b2l[t] = b2d[t];
    }
    for (int i = t; i < 1536; i += 256) w2l[i] = w2d[i];
    const float mask_n = maskp[n];
    __syncthreads();

    const int cg = t & 3, pr = t >> 2;
#pragma unroll
    for (int half = 0; half < 2; ++half) {
        const int mm = half * 64 + pr;
        const int m = mt * 128 + mm;
        const float* p = in2d + ((size_t)n * 768 + m) * 128 + cg * 32;
        float acc[12] = {0,0,0,0,0,0,0,0,0,0,0,0};
#pragma unroll
        for (int cq = 0; cq < 8; ++cq) {
            const float4 v = *reinterpret_cast<const float4*>(p + cq * 4);
#pragma unroll
            for (int j = 0; j < 4; ++j) {
                const float x = (&v.x)[j];
                const int c = cg * 32 + cq * 4 + j;
#pragma unroll
                for (int h = 0; h < 12; ++h) acc[h] += x * w2l[c * 12 + h];
            }
        }
#pragma unroll
        for (int h = 0; h < 12; ++h) {
            acc[h] += __shfl_xor(acc[h], 1);
            acc[h] += __shfl_xor(acc[h], 2);
        }
        if (cg == 0) {
#pragma unroll
            for (int h = 0; h < 12; ++h)
                a2l[h][mm] = (acc[h] + b2l[h]) * RSQRT3;
        }
    }
    __syncthreads();

    const float* kst = ws + OFF_KST;
    const float* kpt = ws + OFF_KPT;
#pragma unroll
    for (int i = 0; i < 6; ++i) {
        const int idx = i * 256 + t;
        const int h = idx >> 7, mm = idx & 127;
        const int m = mt * 128 + mm;
        float sc = 0.f;
        const float* ks = kst + (size_t)(h*16)*768 + m;
#pragma unroll
        for (int k = 0; k < 16; ++k) sc += qs[h*16 + k] * ks[(size_t)k*768];
        float d2 = 0.f;
        const float* kp = kpt + (size_t)(h*12)*768 + m;
#pragma unroll
        for (int d = 0; d < 12; ++d) {
            const int ii = d >> 2, a = d & 3;
            const float dq = qpl[ii*48 + h*4 + a] - kp[(size_t)d*768];
            d2 += dq * dq;
        }
        const float pen = FP16HUGE * (1.f - mask_n * maskp[m]);
        ws[OFF_LG + ((size_t)n * 12 + h) * 768 + m] =
            sc - 0.5f * pwl[h] * d2 - pen + a2l[h][mm];
    }
}

// ---------------------------------------------------------------------------
// FUSED softmax + vsp + v2d + epi + norm: one block (512 thr) per row n.
// ---------------------------------------------------------------------------
__global__ __launch_bounds__(512) void k_att(const float* __restrict__ in2d,
    const float* __restrict__ trans, float* __restrict__ ws)
{
    __shared__ float at[12][776];
    __shared__ float fl[480];
    __shared__ float ptl[288];
    __shared__ float Rl[9], trl[3];
    const int n = blockIdx.x, t = threadIdx.x;
    const int wv = t >> 6, lane = t & 63;
    if (t < 9) Rl[t] = ws[OFF_R + n*9 + t];
    if (t < 3) trl[t] = trans[n*3 + t];
    {
        const float4* a4 = reinterpret_cast<const float4*>(ws + OFF_LG + (size_t)n * 9216);
        for (int i = t; i < 2304; i += 512) {
            const int row = i / 192, j = i - row * 192;
            *reinterpret_cast<float4*>(&at[row][j * 4]) = a4[i];
        }
    }
    __syncthreads();

    for (int h = wv; h < 12; h += 8) {
        float v[12];
        float mx = -3.0e38f;
#pragma unroll
        for (int i = 0; i < 12; ++i) { v[i] = at[h][lane + i*64]; mx = fmaxf(mx, v[i]); }
#pragma unroll
        for (int off = 32; off > 0; off >>= 1) mx = fmaxf(mx, __shfl_xor(mx, off));
        float s = 0.f;
#pragma unroll
        for (int i = 0; i < 12; ++i) { v[i] = expf(v[i] - mx); s += v[i]; }
#pragma unroll
        for (int off = 32; off > 0; off >>= 1) s += __shfl_xor(s, off);
        const float inv = 1.f / s;
#pragma unroll
        for (int i = 0; i < 12; ++i) at[h][lane + i*64] = v[i] * inv;
    }
    __syncthreads();

    // res_2d: group g = t>>7 owns 3 heads; c = t&127
    {
        const int c = t & 127, g = t >> 7;
        const float* p = in2d + (size_t)n * 768 * 128 + c;
        float a0 = 0.f, a1 = 0.f, a2 = 0.f;
        for (int m = 0; m < 768; ++m) {
            const float x = p[(size_t)m * 128];
            a0 += at[g*3+0][m] * x;
            a1 += at[g*3+1][m] * x;
            a2 += at[g*3+2][m] * x;
        }
        float* fo = ws + OFF_FIN + (size_t)n * 2112 + 576;
        fo[(g*3+0)*128 + c] = a0;
        fo[(g*3+1)*128 + c] = a1;
        fo[(g*3+2)*128 + c] = a2;
    }

    // res_s + res_pt_g via VCAT -> fl
    if (t < 480) {
        int h;
        if (t < 192) h = t >> 4;
        else { const int r = (t - 192) % 96; h = r >> 3; }
        const float* v = ws + OFF_VCAT + t;
        const float* a = &at[h][0];
        float s = 0.f;
        for (int m = 0; m < 768; ++m) s += a[m] * v[(size_t)m * 480];
        fl[t] = s;
    }
    __syncthreads();

    float* fo = ws + OFF_FIN + (size_t)n * 2112;
    if (t < 192) fo[t] = fl[t];                    // res_s
    if (t < 288) {                                 // res_pt_l
        const int i = t / 96, p = t - 96 * i;
        float s = 0.f;
#pragma unroll
        for (int j = 0; j < 3; ++j)
            s += Rl[j*3 + i] * (fl[192 + j*96 + p] - trl[j]);
        fo[192 + t] = s;
        ptl[t] = s;
    }
    __syncthreads();
    if (t < 96) {                                  // pt_norm
        const float a = ptl[t], b = ptl[96 + t], c = ptl[192 + t];
        fo[480 + t] = sqrtf(1e-8f + a*a + b*b + c*c);
    }
}

// Final GEMM v2 (unchanged)
__global__ __launch_bounds__(256) void k_final(const float* __restrict__ wout,
    const float* __restrict__ bout, const float* __restrict__ ws,
    float* __restrict__ out)
{
    __shared__ float At[8][64];
    __shared__ float Bt[64][132];
    const float* fin = ws + OFF_FIN;
    const int r0 = blockIdx.y * 8;
    const int c0 = blockIdx.x * 128;
    const int t = threadIdx.x;
    const int c = t & 127, half = t >> 7;
    float acc[4] = {0.f, 0.f, 0.f, 0.f};
    for (int k0 = 0; k0 < 2112; k0 += 64) {
        __syncthreads();
        if (t < 128) {
            const int r = t >> 4, j = t & 15;
            *reinterpret_cast<float4*>(&At[r][j * 4]) =
                *reinterpret_cast<const float4*>(&fin[(size_t)(r0 + r) * 2112 + k0 + j * 4]);
        }
#pragma unroll
        for (int i = t; i < 2048; i += 256) {
            const int k = i >> 5, j = i & 31;
            *reinterpret_cast<float4*>(&Bt[k][j * 4]) =
                *reinterpret_cast<const float4*>(&wout[(size_t)(k0 + k) * 384 + c0 + j * 4]);
        }
        __syncthreads();
#pragma unroll
        for (int k = 0; k < 64; ++k) {
            const float b = Bt[k][c];
#pragma unroll
            for (int r = 0; r < 4; ++r) acc[r] += At[half*4 + r][k] * b;
        }
    }
#pragma unroll
    for (int r = 0; r < 4; ++r)
        out[(size_t)(r0 + half*4 + r) * 384 + c0 + c] = acc[r] + bout[c0 + c];
}

// ---------------------------------------------------------------------------
extern "C" void kernel_launch(void* const* d_in, const int* in_sizes, int n_in,
                              void* d_out, int out_size, void* d_ws, size_t ws_size,
                              hipStream_t stream)
{
    const float* in1d  = (const float*)d_in[0];
    const float* in2d  = (const float*)d_in[1];
    const float* maskp = (const float*)d_in[2];
    const float* quat  = (const float*)d_in[3];
    const float* trans = (const float*)d_in[4];
    const float* wq    = (const float*)d_in[5];
    const float* bq    = (const float*)d_in[6];
    const float* wkv   = (const float*)d_in[7];
    const float* bkv   = (const float*)d_in[8];
    const float* wqp   = (const float*)d_in[9];
    const float* bqp   = (const float*)d_in[10];
    const float* wkvp  = (const float*)d_in[11];
    const float* bkvp  = (const float*)d_in[12];
    const float* pwr   = (const float*)d_in[13];
    const float* w2d   = (const float*)d_in[14];
    const float* b2d   = (const float*)d_in[15];
    const float* wout  = (const float*)d_in[16];
    const float* bout  = (const float*)d_in[17];
    float* ws  = (float*)d_ws;
    float* out = (float*)d_out;

    if (ws_size < WS_TOTAL * sizeof(float)) {
        const float val = 1000.0f + (float)(ws_size / (1024.0 * 1024.0));
        k_sentinel<<<dim3((out_size + 255) / 256), dim3(256), 0, stream>>>(out, out_size, val);
        return;
    }

    dim3 blk(256);
    k_proj_all<<<dim3(2, 96, 4), blk, 0, stream>>>(in1d, wq, bq, wkv, bkv,
                                                   wqp, bqp, wkvp, bkvp, ws);
    k_rmat<<<dim3((768*9 + 255)/256), blk, 0, stream>>>(quat, ws);
    k_rigid<<<dim3((768*576 + 255)/256), blk, 0, stream>>>(trans, ws);
    k_vcat<<<dim3((768*480 + 255)/256), blk, 0, stream>>>(ws);
    k_kt<<<dim3((768*336 + 255)/256), blk, 0, stream>>>(ws);
    k_lga<<<dim3(768, 6), blk, 0, stream>>>(in2d, w2d, b2d, maskp, pwr, ws);
    k_att<<<dim3(768), dim3(512), 0, stream>>>(in2d, trans, ws);
    k_final<<<dim3(3, 96), blk, 0, stream>>>(wout, bout, ws, out);
}

// Round 13
// 525.559 us; speedup vs baseline: 2.6516x; 1.0002x over previous
//
#include <hip/hip_runtime.h>
#include <cstdint>
#include <cstddef>

// B=1, N=768, CM=384, CP=128, H=12, SQK=SV=16, PQK=4, PV=8, NFIN=2112, NOUT=384
static constexpr float SCALAR_W = 0.14433756729740643f;  // 1/sqrt(3*16)
static constexpr float PTW_C    = 0.13608276348795434f;  // sqrt(1/(3*4*4.5))
static constexpr float RSQRT3   = 0.5773502691896258f;
static constexpr float FP16HUGE = 65504.0f;

// ws layout (floats)
static constexpr size_t OFF_P    = 0;          // 768*1152  [n][ q(192) | kv(384) | qp(144) | kvp(432) ]
static constexpr size_t OFF_R    = 884736;     // 768*9     [n][i*3+j]
static constexpr size_t OFF_QPG  = 891648;     // 768*144   [n][i*48 + h*4 + a]
static constexpr size_t OFF_KVPG = 1002240;    // 768*432   [n][i*144 + h*12 + e]
static constexpr size_t OFF_LG   = 1334016;    // 768*12*768  [n][h][m]
static constexpr size_t OFF_FIN  = 8633088;    // 768*2112
static constexpr size_t OFF_VCAT = 10255104;   // 768*480   [m][ v_s(192) | vp_g(288) ]
static constexpr size_t OFF_KST  = 10623744;   // 12*16*768 [h][k][m]
static constexpr size_t OFF_KPT  = 10771200;   // 12*12*768 [h][d][m]
static constexpr size_t WS_TOTAL = 10881792;   // floats = 43.5 MB

__global__ void k_sentinel(float* __restrict__ out, int nel, float val)
{
    const int i = blockIdx.x * 256 + threadIdx.x;
    if (i < nel) out[i] = val;
}

// ---------------------------------------------------------------------------
// All four projections in one launch. grid (2, 96, 4); z selects matrix.
// ---------------------------------------------------------------------------
__global__ __launch_bounds__(256) void k_proj_all(const float* __restrict__ A,
    const float* __restrict__ wq,  const float* __restrict__ bq,
    const float* __restrict__ wkv, const float* __restrict__ bkv,
    const float* __restrict__ wqp, const float* __restrict__ bqp,
    const float* __restrict__ wkvp,const float* __restrict__ bkvp,
    float* __restrict__ P)
{
    const int z = blockIdx.z;
    const float* Bm; const float* bias; int ncols, colbase;
    switch (z) {
        case 0: Bm = wq;   bias = bq;   ncols = 192; colbase = 0;   break;
        case 1: Bm = wkv;  bias = bkv;  ncols = 384; colbase = 192; break;
        case 2: Bm = wqp;  bias = bqp;  ncols = 144; colbase = 576; break;
        default:Bm = wkvp; bias = bkvp; ncols = 432; colbase = 720; break;
    }
    if (blockIdx.x * 256 >= ncols) return;
    __shared__ float At[8][384];
    const int t = threadIdx.x;
    const int r0 = blockIdx.y * 8;
    const float4* A4 = reinterpret_cast<const float4*>(A + (size_t)r0 * 384);
    float4* At4 = reinterpret_cast<float4*>(&At[0][0]);
#pragma unroll
    for (int i = 0; i < 3; ++i) At4[t + 256 * i] = A4[t + 256 * i];
    __syncthreads();
    const int col = blockIdx.x * 256 + t;
    if (col >= ncols) return;
    float acc[8] = {0.f,0.f,0.f,0.f,0.f,0.f,0.f,0.f};
    const float* bp = Bm + col;
#pragma unroll 4
    for (int k = 0; k < 384; ++k) {
        const float b = bp[(size_t)k * ncols];
#pragma unroll
        for (int r = 0; r < 8; ++r) acc[r] += At[r][k] * b;
    }
    const float bb = bias[col];
#pragma unroll
    for (int r = 0; r < 8; ++r)
        P[(size_t)(r0 + r) * 1152 + colbase + col] = acc[r] + bb;
}

// R[n][i][j]  (R9-proven)
__global__ __launch_bounds__(256) void k_rmat(const float* __restrict__ quat,
    float* __restrict__ ws)
{
    const int o = blockIdx.x * 256 + threadIdx.x;
    if (o >= 768 * 9) return;
    const int n = o / 9, e = o - 9 * n;
    const float q0 = quat[n*4+0], q1 = quat[n*4+1], q2 = quat[n*4+2], q3 = quat[n*4+3];
    const float inv = 1.0f / sqrtf(q0*q0 + q1*q1 + q2*q2 + q3*q3);
    const float w = q0*inv, x = q1*inv, y = q2*inv, z = q3*inv;
    float R[9];
    R[0] = 1.f - 2.f*(y*y + z*z); R[1] = 2.f*(x*y - w*z); R[2] = 2.f*(x*z + w*y);
    R[3] = 2.f*(x*y + w*z); R[4] = 1.f - 2.f*(x*x + z*z); R[5] = 2.f*(y*z - w*x);
    R[6] = 2.f*(x*z - w*y); R[7] = 2.f*(y*z + w*x); R[8] = 1.f - 2.f*(x*x + y*y);
    ws[OFF_R + o] = R[e];
}

// qp_g / kvp_g  (R9-proven)
__global__ __launch_bounds__(256) void k_rigid(const float* __restrict__ trans,
    float* __restrict__ ws)
{
    const int o = blockIdx.x * 256 + threadIdx.x;
    if (o >= 768 * 576) return;
    const int n = o / 576, e = o - 576 * n;
    const float* R = ws + OFF_R + (size_t)n * 9;
    if (e < 144) {
        const int i = e / 48, p = e - 48 * i;
        const float* Pn = ws + OFF_P + (size_t)n * 1152 + 576;
        ws[OFF_QPG + (size_t)n*144 + e] =
            R[i*3+0]*Pn[p] + R[i*3+1]*Pn[48+p] + R[i*3+2]*Pn[96+p] + trans[n*3+i];
    } else {
        const int e2 = e - 144;
        const int i = e2 / 144, p = e2 - 144 * i;
        const float* Pn = ws + OFF_P + (size_t)n * 1152 + 720;
        ws[OFF_KVPG + (size_t)n*432 + e2] =
            R[i*3+0]*Pn[p] + R[i*3+1]*Pn[144+p] + R[i*3+2]*Pn[288+p] + trans[n*3+i];
    }
}

// VCAT[m][480]  (R9-proven)
__global__ __launch_bounds__(256) void k_vcat(float* __restrict__ ws)
{
    const int o = blockIdx.x * 256 + threadIdx.x;
    if (o >= 768 * 480) return;
    const int m = o / 480, q = o - 480 * m;
    float v;
    if (q < 192) {
        const int h = q >> 4, d = q & 15;
        v = ws[OFF_P + (size_t)m*1152 + 192 + h*32 + 16 + d];
    } else {
        const int q2 = q - 192;
        const int i = q2 / 96, r = q2 - 96*i, h = r >> 3, c = r & 7;
        v = ws[OFF_KVPG + (size_t)m*432 + i*144 + h*12 + 4 + c];
    }
    ws[OFF_VCAT + o] = v;
}

// k-side transposes  (R9-proven)
__global__ __launch_bounds__(256) void k_kt(float* __restrict__ ws)
{
    const int o = blockIdx.x * 256 + threadIdx.x;
    if (o >= 768 * 336) return;
    const int m = o / 336, q = o - 336 * m;
    if (q < 192) {
        const int h = q >> 4, k = q & 15;
        ws[OFF_KST + (size_t)(h*16 + k)*768 + m] =
            ws[OFF_P + (size_t)m*1152 + 192 + h*32 + k];
    } else {
        const int d2 = q - 192;
        const int h = d2 / 12, d = d2 - 12 * h;
        const int i = d >> 2, a = d & 3;
        ws[OFF_KPT + (size_t)(h*12 + d)*768 + m] =
            ws[OFF_KVPG + (size_t)m*432 + i*144 + h*12 + a];
    }
}

// ---------------------------------------------------------------------------
// FUSED logits + a2d  (R9-proven, unchanged)
// ---------------------------------------------------------------------------
__global__ __launch_bounds__(256) void k_lga(const float* __restrict__ in2d,
    const float* __restrict__ w2d, const float* __restrict__ b2d,
    const float* __restrict__ maskp, const float* __restrict__ pw_raw,
    float* __restrict__ ws)
{
    __shared__ float w2l[1536];
    __shared__ float a2l[12][132];
    __shared__ float qs[192], qpl[144], pwl[12], b2l[12];
    const int n = blockIdx.x, mt = blockIdx.y, t = threadIdx.x;
    if (t < 192) qs[t] = ws[OFF_P + (size_t)n*1152 + t] * SCALAR_W;
    if (t < 144) qpl[t] = ws[OFF_QPG + (size_t)n*144 + t];
    if (t < 12) {
        pwl[t] = PTW_C * logf(1.f + expf(pw_raw[t]));
        b2l[t] = b2d[t];
    }
    for (int i = t; i < 1536; i += 256) w2l[i] = w2d[i];
    const float mask_n = maskp[n];
    __syncthreads();

    const int cg = t & 3, pr = t >> 2;
#pragma unroll
    for (int half = 0; half < 2; ++half) {
        const int mm = half * 64 + pr;
        const int m = mt * 128 + mm;
        const float* p = in2d + ((size_t)n * 768 + m) * 128 + cg * 32;
        float acc[12] = {0,0,0,0,0,0,0,0,0,0,0,0};
#pragma unroll
        for (int cq = 0; cq < 8; ++cq) {
            const float4 v = *reinterpret_cast<const float4*>(p + cq * 4);
#pragma unroll
            for (int j = 0; j < 4; ++j) {
                const float x = (&v.x)[j];
                const int c = cg * 32 + cq * 4 + j;
#pragma unroll
                for (int h = 0; h < 12; ++h) acc[h] += x * w2l[c * 12 + h];
            }
        }
#pragma unroll
        for (int h = 0; h < 12; ++h) {
            acc[h] += __shfl_xor(acc[h], 1);
            acc[h] += __shfl_xor(acc[h], 2);
        }
        if (cg == 0) {
#pragma unroll
            for (int h = 0; h < 12; ++h)
                a2l[h][mm] = (acc[h] + b2l[h]) * RSQRT3;
        }
    }
    __syncthreads();

    const float* kst = ws + OFF_KST;
    const float* kpt = ws + OFF_KPT;
#pragma unroll
    for (int i = 0; i < 6; ++i) {
        const int idx = i * 256 + t;
        const int h = idx >> 7, mm = idx & 127;
        const int m = mt * 128 + mm;
        float sc = 0.f;
        const float* ks = kst + (size_t)(h*16)*768 + m;
#pragma unroll
        for (int k = 0; k < 16; ++k) sc += qs[h*16 + k] * ks[(size_t)k*768];
        float d2 = 0.f;
        const float* kp = kpt + (size_t)(h*12)*768 + m;
#pragma unroll
        for (int d = 0; d < 12; ++d) {
            const int ii = d >> 2, a = d & 3;
            const float dq = qpl[ii*48 + h*4 + a] - kp[(size_t)d*768];
            d2 += dq * dq;
        }
        const float pen = FP16HUGE * (1.f - mask_n * maskp[m]);
        ws[OFF_LG + ((size_t)n * 12 + h) * 768 + m] =
            sc - 0.5f * pwl[h] * d2 - pen + a2l[h][mm];
    }
}

// ---------------------------------------------------------------------------
// FUSED softmax + vsp + v2d + epi + norm: one block (512 thr) per row n.
// ---------------------------------------------------------------------------
__global__ __launch_bounds__(512) void k_att(const float* __restrict__ in2d,
    const float* __restrict__ trans, float* __restrict__ ws)
{
    __shared__ float at[12][776];
    __shared__ float fl[480];
    __shared__ float ptl[288];
    __shared__ float Rl[9], trl[3];
    const int n = blockIdx.x, t = threadIdx.x;
    const int wv = t >> 6, lane = t & 63;
    if (t < 9) Rl[t] = ws[OFF_R + n*9 + t];
    if (t < 3) trl[t] = trans[n*3 + t];
    {
        const float4* a4 = reinterpret_cast<const float4*>(ws + OFF_LG + (size_t)n * 9216);
        for (int i = t; i < 2304; i += 512) {
            const int row = i / 192, j = i - row * 192;
            *reinterpret_cast<float4*>(&at[row][j * 4]) = a4[i];
        }
    }
    __syncthreads();

    for (int h = wv; h < 12; h += 8) {
        float v[12];
        float mx = -3.0e38f;
#pragma unroll
        for (int i = 0; i < 12; ++i) { v[i] = at[h][lane + i*64]; mx = fmaxf(mx, v[i]); }
#pragma unroll
        for (int off = 32; off > 0; off >>= 1) mx = fmaxf(mx, __shfl_xor(mx, off));
        float s = 0.f;
#pragma unroll
        for (int i = 0; i < 12; ++i) { v[i] = expf(v[i] - mx); s += v[i]; }
#pragma unroll
        for (int off = 32; off > 0; off >>= 1) s += __shfl_xor(s, off);
        const float inv = 1.f / s;
#pragma unroll
        for (int i = 0; i < 12; ++i) at[h][lane + i*64] = v[i] * inv;
    }
    __syncthreads();

    // res_2d: group g = t>>7 owns 3 heads; c = t&127
    {
        const int c = t & 127, g = t >> 7;
        const float* p = in2d + (size_t)n * 768 * 128 + c;
        float a0 = 0.f, a1 = 0.f, a2 = 0.f;
        for (int m = 0; m < 768; ++m) {
            const float x = p[(size_t)m * 128];
            a0 += at[g*3+0][m] * x;
            a1 += at[g*3+1][m] * x;
            a2 += at[g*3+2][m] * x;
        }
        float* fo = ws + OFF_FIN + (size_t)n * 2112 + 576;
        fo[(g*3+0)*128 + c] = a0;
        fo[(g*3+1)*128 + c] = a1;
        fo[(g*3+2)*128 + c] = a2;
    }

    // res_s + res_pt_g via VCAT -> fl
    if (t < 480) {
        int h;
        if (t < 192) h = t >> 4;
        else { const int r = (t - 192) % 96; h = r >> 3; }
        const float* v = ws + OFF_VCAT + t;
        const float* a = &at[h][0];
        float s = 0.f;
        for (int m = 0; m < 768; ++m) s += a[m] * v[(size_t)m * 480];
        fl[t] = s;
    }
    __syncthreads();

    float* fo = ws + OFF_FIN + (size_t)n * 2112;
    if (t < 192) fo[t] = fl[t];                    // res_s
    if (t < 288) {                                 // res_pt_l
        const int i = t / 96, p = t - 96 * i;
        float s = 0.f;
#pragma unroll
        for (int j = 0; j < 3; ++j)
            s += Rl[j*3 + i] * (fl[192 + j*96 + p] - trl[j]);
        fo[192 + t] = s;
        ptl[t] = s;
    }
    __syncthreads();
    if (t < 96) {                                  // pt_norm
        const float a = ptl[t], b = ptl[96 + t], c = ptl[192 + t];
        fo[480 + t] = sqrtf(1e-8f + a*a + b*b + c*c);
    }
}

// Final GEMM v2 (unchanged)
__global__ __launch_bounds__(256) void k_final(const float* __restrict__ wout,
    const float* __restrict__ bout, const float* __restrict__ ws,
    float* __restrict__ out)
{
    __shared__ float At[8][64];
    __shared__ float Bt[64][132];
    const float* fin = ws + OFF_FIN;
    const int r0 = blockIdx.y * 8;
    const int c0 = blockIdx.x * 128;
    const int t = threadIdx.x;
    const int c = t & 127, half = t >> 7;
    float acc[4] = {0.f, 0.f, 0.f, 0.f};
    for (int k0 = 0; k0 < 2112; k0 += 64) {
        __syncthreads();
        if (t < 128) {
            const int r = t >> 4, j = t & 15;
            *reinterpret_cast<float4*>(&At[r][j * 4]) =
                *reinterpret_cast<const float4*>(&fin[(size_t)(r0 + r) * 2112 + k0 + j * 4]);
        }
#pragma unroll
        for (int i = t; i < 2048; i += 256) {
            const int k = i >> 5, j = i & 31;
            *reinterpret_cast<float4*>(&Bt[k][j * 4]) =
                *reinterpret_cast<const float4*>(&wout[(size_t)(k0 + k) * 384 + c0 + j * 4]);
        }
        __syncthreads();
#pragma unroll
        for (int k = 0; k < 64; ++k) {
            const float b = Bt[k][c];
#pragma unroll
            for (int r = 0; r < 4; ++r) acc[r] += At[half*4 + r][k] * b;
        }
    }
#pragma unroll
    for (int r = 0; r < 4; ++r)
        out[(size_t)(r0 + half*4 + r) * 384 + c0 + c] = acc[r] + bout[c0 + c];
}

// ---------------------------------------------------------------------------
extern "C" void kernel_launch(void* const* d_in, const int* in_sizes, int n_in,
                              void* d_out, int out_size, void* d_ws, size_t ws_size,
                              hipStream_t stream)
{
    const float* in1d  = (const float*)d_in[0];
    const float* in2d  = (const float*)d_in[1];
    const float* maskp = (const float*)d_in[2];
    const float* quat  = (const float*)d_in[3];
    const float* trans = (const float*)d_in[4];
    const float* wq    = (const float*)d_in[5];
    const float* bq    = (const float*)d_in[6];
    const float* wkv   = (const float*)d_in[7];
    const float* bkv   = (const float*)d_in[8];
    const float* wqp   = (const float*)d_in[9];
    const float* bqp   = (const float*)d_in[10];
    const float* wkvp  = (const float*)d_in[11];
    const float* bkvp  = (const float*)d_in[12];
    const float* pwr   = (const float*)d_in[13];
    const float* w2d   = (const float*)d_in[14];
    const float* b2d   = (const float*)d_in[15];
    const float* wout  = (const float*)d_in[16];
    const float* bout  = (const float*)d_in[17];
    float* ws  = (float*)d_ws;
    float* out = (float*)d_out;

    if (ws_size < WS_TOTAL * sizeof(float)) {
        const float val = 1000.0f + (float)(ws_size / (1024.0 * 1024.0));
        k_sentinel<<<dim3((out_size + 255) / 256), dim3(256), 0, stream>>>(out, out_size, val);
        return;
    }

    dim3 blk(256);
    k_proj_all<<<dim3(2, 96, 4), blk, 0, stream>>>(in1d, wq, bq, wkv, bkv,
                                                   wqp, bqp, wkvp, bkvp, ws);
    k_rmat<<<dim3((768*9 + 255)/256), blk, 0, stream>>>(quat, ws);
    k_rigid<<<dim3((768*576 + 255)/256), blk, 0, stream>>>(trans, ws);
    k_vcat<<<dim3((768*480 + 255)/256), blk, 0, stream>>>(ws);
    k_kt<<<dim3((768*336 + 255)/256), blk, 0, stream>>>(ws);
    k_lga<<<dim3(768, 6), blk, 0, stream>>>(in2d, w2d, b2d, maskp, pwr, ws);
    k_att<<<dim3(768), dim3(512), 0, stream>>>(in2d, trans, ws);
    k_final<<<dim3(3, 96), blk, 0, stream>>>(wout, bout, ws, out);
}